// Round 1
// baseline (3953.507 us; speedup 1.0000x reference)
//
#include <hip/hip_runtime.h>
#include <hip/hip_bf16.h>
#include <math.h>

#define B_SZ 1024
#define S_SZ 40
#define H_SZ 1024
#define DW_SZ 512
#define V_SZ 4000

__device__ __forceinline__ float fast_tanh(float x) {
    // 1 - 2/(1+exp(2x)); saturates correctly for large |x|
    return 1.0f - 2.0f / (1.0f + __expf(2.0f * x));
}
__device__ __forceinline__ float fast_sigmoid(float x) {
    return 1.0f / (1.0f + __expf(-x));
}

// C[m,n] = sum_k A[m,k] * W[n,k] + bias[n]
// BM=BN=64, BK=16, 256 threads, 4x4 microtile. M must be multiple of 64 (true for all calls).
__global__ __launch_bounds__(256) void gemm_bt_f32(
    const float* __restrict__ A, int lda,
    const float* __restrict__ W, int ldw,
    const float* __restrict__ bias,
    float* __restrict__ C, int ldc,
    int N, int K) {
    __shared__ float As[16][65];
    __shared__ float Ws[16][65];
    const int tid = threadIdx.x;
    const int bm = blockIdx.y * 64;
    const int bn = blockIdx.x * 64;
    const int tx = tid & 15, ty = tid >> 4;
    const int lrow = tid >> 2;          // 0..63
    const int lk = (tid & 3) << 2;      // 0,4,8,12
    float acc[4][4] = {};

    const float* Aptr = A + (size_t)(bm + lrow) * lda + lk;
    const int wrow = bn + lrow;
    const float* Wptr = W + (size_t)wrow * ldw + lk;

    for (int k0 = 0; k0 < K; k0 += 16) {
        float4 av = *reinterpret_cast<const float4*>(Aptr + k0);
        float4 wv = make_float4(0.f, 0.f, 0.f, 0.f);
        if (wrow < N) wv = *reinterpret_cast<const float4*>(Wptr + k0);
        __syncthreads();
        As[lk + 0][lrow] = av.x; As[lk + 1][lrow] = av.y;
        As[lk + 2][lrow] = av.z; As[lk + 3][lrow] = av.w;
        Ws[lk + 0][lrow] = wv.x; Ws[lk + 1][lrow] = wv.y;
        Ws[lk + 2][lrow] = wv.z; Ws[lk + 3][lrow] = wv.w;
        __syncthreads();
#pragma unroll
        for (int kk = 0; kk < 16; ++kk) {
            float a0 = As[kk][ty * 4 + 0];
            float a1 = As[kk][ty * 4 + 1];
            float a2 = As[kk][ty * 4 + 2];
            float a3 = As[kk][ty * 4 + 3];
            float w0 = Ws[kk][tx * 4 + 0];
            float w1 = Ws[kk][tx * 4 + 1];
            float w2 = Ws[kk][tx * 4 + 2];
            float w3 = Ws[kk][tx * 4 + 3];
            acc[0][0] += a0 * w0; acc[0][1] += a0 * w1; acc[0][2] += a0 * w2; acc[0][3] += a0 * w3;
            acc[1][0] += a1 * w0; acc[1][1] += a1 * w1; acc[1][2] += a1 * w2; acc[1][3] += a1 * w3;
            acc[2][0] += a2 * w0; acc[2][1] += a2 * w1; acc[2][2] += a2 * w2; acc[2][3] += a2 * w3;
            acc[3][0] += a3 * w0; acc[3][1] += a3 * w1; acc[3][2] += a3 * w2; acc[3][3] += a3 * w3;
        }
    }

    const int n0 = bn + tx * 4;
    float b0 = 0.f, b1 = 0.f, b2 = 0.f, b3 = 0.f;
    if (bias) {
        if (n0 + 0 < N) b0 = bias[n0 + 0];
        if (n0 + 1 < N) b1 = bias[n0 + 1];
        if (n0 + 2 < N) b2 = bias[n0 + 2];
        if (n0 + 3 < N) b3 = bias[n0 + 3];
    }
#pragma unroll
    for (int i = 0; i < 4; ++i) {
        const int m = bm + ty * 4 + i;
        float* crow = C + (size_t)m * ldc;
        if (n0 + 3 < N) {
            float4 v = make_float4(acc[i][0] + b0, acc[i][1] + b1, acc[i][2] + b2, acc[i][3] + b3);
            *reinterpret_cast<float4*>(crow + n0) = v;
        } else {
            if (n0 + 0 < N) crow[n0 + 0] = acc[i][0] + b0;
            if (n0 + 1 < N) crow[n0 + 1] = acc[i][1] + b1;
            if (n0 + 2 < N) crow[n0 + 2] = acc[i][2] + b2;
            if (n0 + 3 < N) crow[n0 + 3] = acc[i][3] + b3;
        }
    }
}

// One block per batch row b. 256 threads; each owns 4 h-positions (256*4 == H).
// e[s] = sum_h tanh(enc_proj[b,s,h] + hproj[b,h]) * w2[h]; softmax over S; ctx = sum_s alpha*enc.
__global__ __launch_bounds__(256) void attn_ctx_kernel(
    const float* __restrict__ enc,
    const float* __restrict__ enc_proj,
    const float* __restrict__ hproj,   // already includes b1
    const float* __restrict__ w2,
    float* __restrict__ ctx) {
    const int b = blockIdx.x;
    const int tid = threadIdx.x;
    const int lane = tid & 63, wave = tid >> 6;
    __shared__ float s_e[S_SZ];
    __shared__ float s_red[4];

    const float4 hp = reinterpret_cast<const float4*>(hproj + (size_t)b * H_SZ)[tid];
    const float4 w24 = reinterpret_cast<const float4*>(w2)[tid];
    const float4* ep_base = reinterpret_cast<const float4*>(enc_proj + (size_t)b * S_SZ * H_SZ);

    for (int s = 0; s < S_SZ; ++s) {
        float4 ep = ep_base[s * 256 + tid];
        float p = fast_tanh(ep.x + hp.x) * w24.x
                + fast_tanh(ep.y + hp.y) * w24.y
                + fast_tanh(ep.z + hp.z) * w24.z
                + fast_tanh(ep.w + hp.w) * w24.w;
#pragma unroll
        for (int off = 32; off > 0; off >>= 1) p += __shfl_down(p, off);
        if (lane == 0) s_red[wave] = p;
        __syncthreads();
        if (tid == 0) s_e[s] = s_red[0] + s_red[1] + s_red[2] + s_red[3];
        __syncthreads();
    }

    float m = -1e30f;
    for (int s = 0; s < S_SZ; ++s) m = fmaxf(m, s_e[s]);
    float sum = 0.f;
    for (int s = 0; s < S_SZ; ++s) sum += __expf(s_e[s] - m);
    const float inv = 1.0f / sum;

    const float4* enc_b = reinterpret_cast<const float4*>(enc + (size_t)b * S_SZ * H_SZ);
    float4 acc = make_float4(0.f, 0.f, 0.f, 0.f);
    for (int s = 0; s < S_SZ; ++s) {
        const float a = __expf(s_e[s] - m) * inv;
        float4 ev = enc_b[s * 256 + tid];
        acc.x += a * ev.x; acc.y += a * ev.y; acc.z += a * ev.z; acc.w += a * ev.w;
    }
    reinterpret_cast<float4*>(ctx + (size_t)b * H_SZ)[tid] = acc;
}

// x[b] = [emb[it[b]], ctx[b]]
__global__ __launch_bounds__(256) void build_x_kernel(
    const float* __restrict__ emb,
    const int* __restrict__ targets,
    const float* __restrict__ ctx,
    float* __restrict__ x, int t) {
    const int b = blockIdx.x;
    const int tid = threadIdx.x;
    int it;
    if (t == 0) it = 0;
    else if (t == 1) it = targets[b] + 1;
    else it = targets[B_SZ + b] + 36;
    float4* x4 = reinterpret_cast<float4*>(x + (size_t)b * (DW_SZ + H_SZ));
    if (tid < DW_SZ / 4) {
        x4[tid] = reinterpret_cast<const float4*>(emb + (size_t)it * DW_SZ)[tid];
    }
    x4[DW_SZ / 4 + tid] = reinterpret_cast<const float4*>(ctx + (size_t)b * H_SZ)[tid];
}

// h = (1-z)*n + z*h  (in place)
__global__ __launch_bounds__(256) void gru_gate_kernel(
    const float* __restrict__ gi,
    const float* __restrict__ gh,
    float* __restrict__ h) {
    const int idx = blockIdx.x * 256 + threadIdx.x;   // over B*H
    const int b = idx >> 10;
    const int j = idx & 1023;
    const float* gib = gi + (size_t)b * 3 * H_SZ;
    const float* ghb = gh + (size_t)b * 3 * H_SZ;
    const float i_r = gib[j], i_z = gib[H_SZ + j], i_n = gib[2 * H_SZ + j];
    const float h_r = ghb[j], h_z = ghb[H_SZ + j], h_n = ghb[2 * H_SZ + j];
    const float r = fast_sigmoid(i_r + h_r);
    const float z = fast_sigmoid(i_z + h_z);
    const float n = fast_tanh(i_n + r * h_n);
    h[idx] = (1.0f - z) * n + z * h[idx];
}

// One block per row; out[b, :] = logits[b, :] - (max + log(sum(exp(...-max))))
__global__ __launch_bounds__(256) void logsoftmax_kernel(
    const float* __restrict__ logits,
    float* __restrict__ out) {
    const int b = blockIdx.x;
    const int tid = threadIdx.x;
    const int lane = tid & 63, wave = tid >> 6;
    __shared__ float s_red[4];
    __shared__ float s_bc;
    const float* row = logits + (size_t)b * V_SZ;

    float m = -1e30f;
    for (int k = tid; k < V_SZ; k += 256) m = fmaxf(m, row[k]);
#pragma unroll
    for (int off = 32; off > 0; off >>= 1) m = fmaxf(m, __shfl_down(m, off));
    if (lane == 0) s_red[wave] = m;
    __syncthreads();
    if (tid == 0) s_bc = fmaxf(fmaxf(s_red[0], s_red[1]), fmaxf(s_red[2], s_red[3]));
    __syncthreads();
    m = s_bc;

    float sum = 0.f;
    for (int k = tid; k < V_SZ; k += 256) sum += expf(row[k] - m);
#pragma unroll
    for (int off = 32; off > 0; off >>= 1) sum += __shfl_down(sum, off);
    __syncthreads();   // protect s_red reuse
    if (lane == 0) s_red[wave] = sum;
    __syncthreads();
    if (tid == 0) s_bc = logf(s_red[0] + s_red[1] + s_red[2] + s_red[3]) + m;
    __syncthreads();
    const float ls = s_bc;

    float* orow = out + (size_t)b * V_SZ;
    for (int k = tid; k < V_SZ; k += 256) orow[k] = row[k] - ls;
}

extern "C" void kernel_launch(void* const* d_in, const int* in_sizes, int n_in,
                              void* d_out, int out_size, void* d_ws, size_t ws_size,
                              hipStream_t stream) {
    const float* enc    = (const float*)d_in[0];
    const float* enc_h  = (const float*)d_in[1];
    const int*   tgt    = (const int*)d_in[2];
    const float* emb    = (const float*)d_in[3];
    const float* w1     = (const float*)d_in[4];
    const float* b1     = (const float*)d_in[5];
    const float* w2     = (const float*)d_in[6];
    const float* w_ih   = (const float*)d_in[7];
    const float* w_hh   = (const float*)d_in[8];
    const float* b_ih   = (const float*)d_in[9];
    const float* b_hh   = (const float*)d_in[10];
    const float* out0_w = (const float*)d_in[11];
    const float* out0_b = (const float*)d_in[12];
    const float* out1_w = (const float*)d_in[13];
    const float* out1_b = (const float*)d_in[14];
    float* out = (float*)d_out;

    float* ws = (float*)d_ws;
    float* enc_proj = ws; ws += (size_t)B_SZ * S_SZ * H_SZ;   // 41.9M floats
    float* hproj    = ws; ws += (size_t)B_SZ * H_SZ;
    float* ctx      = ws; ws += (size_t)B_SZ * H_SZ;
    float* x        = ws; ws += (size_t)B_SZ * (DW_SZ + H_SZ);
    float* gi       = ws; ws += (size_t)B_SZ * 3 * H_SZ;
    float* gh       = ws; ws += (size_t)B_SZ * 3 * H_SZ;
    float* h        = ws; ws += (size_t)B_SZ * H_SZ;
    float* logits   = ws; ws += (size_t)B_SZ * V_SZ;

    // h <- encoder_hidden[0]
    hipMemcpyAsync(h, enc_h, (size_t)B_SZ * H_SZ * sizeof(float),
                   hipMemcpyDeviceToDevice, stream);

    // enc_proj = enc @ w1[:, :H].T   (timestep-invariant)
    gemm_bt_f32<<<dim3(H_SZ / 64, (B_SZ * S_SZ) / 64), 256, 0, stream>>>(
        enc, H_SZ, w1, 2 * H_SZ, nullptr, enc_proj, H_SZ, H_SZ, H_SZ);

    for (int t = 0; t < 3; ++t) {
        // hproj = h @ w1[:, H:].T + b1
        gemm_bt_f32<<<dim3(H_SZ / 64, B_SZ / 64), 256, 0, stream>>>(
            h, H_SZ, w1 + H_SZ, 2 * H_SZ, b1, hproj, H_SZ, H_SZ, H_SZ);

        attn_ctx_kernel<<<B_SZ, 256, 0, stream>>>(enc, enc_proj, hproj, w2, ctx);

        build_x_kernel<<<B_SZ, 256, 0, stream>>>(emb, tgt, ctx, x, t);

        // gi = x @ w_ih.T + b_ih
        gemm_bt_f32<<<dim3(3 * H_SZ / 64, B_SZ / 64), 256, 0, stream>>>(
            x, DW_SZ + H_SZ, w_ih, DW_SZ + H_SZ, b_ih, gi, 3 * H_SZ, 3 * H_SZ, DW_SZ + H_SZ);
        // gh = h @ w_hh.T + b_hh
        gemm_bt_f32<<<dim3(3 * H_SZ / 64, B_SZ / 64), 256, 0, stream>>>(
            h, H_SZ, w_hh, H_SZ, b_hh, gh, 3 * H_SZ, 3 * H_SZ, H_SZ);

        gru_gate_kernel<<<(B_SZ * H_SZ) / 256, 256, 0, stream>>>(gi, gh, h);

        const float* ow = (t == 1) ? out1_w : out0_w;
        const float* ob = (t == 1) ? out1_b : out0_b;
        gemm_bt_f32<<<dim3((V_SZ + 63) / 64, B_SZ / 64), 256, 0, stream>>>(
            h, H_SZ, ow, H_SZ, ob, logits, V_SZ, V_SZ, H_SZ);

        logsoftmax_kernel<<<B_SZ, 256, 0, stream>>>(logits, out + (size_t)t * B_SZ * V_SZ);
    }
}

// Round 2
// 792.259 us; speedup vs baseline: 4.9902x; 4.9902x over previous
//
#include <hip/hip_runtime.h>
#include <hip/hip_bf16.h>
#include <math.h>

#define B_SZ 1024
#define S_SZ 40
#define H_SZ 1024
#define DW_SZ 512
#define V_SZ 4000

typedef __bf16 bf16x8 __attribute__((ext_vector_type(8)));
typedef float f32x4 __attribute__((ext_vector_type(4)));

__device__ __forceinline__ float fast_tanh(float x) {
    return 1.0f - 2.0f / (1.0f + __expf(2.0f * x));
}
__device__ __forceinline__ float fast_sigmoid(float x) {
    return 1.0f / (1.0f + __expf(-x));
}
__device__ __forceinline__ float bfraw2f(unsigned short u) {
    return __uint_as_float(((unsigned)u) << 16);
}

#define GLL16(gp, lp)                                                                \
    __builtin_amdgcn_global_load_lds((const __attribute__((address_space(1))) void*)(gp), \
                                     (__attribute__((address_space(3))) void*)(lp), 16, 0, 0)

// ---------------- bf16 MFMA GEMM: C[m,n] = sum_k A[m,k]*W[n,k] + bias[n] ----------------
// 128x128 tile, BK=32, 256 threads (4 waves, 2x2), each wave 64x64 via 4x4 frags of 16x16x32.
// M must be a multiple of 128 (true for all calls). N ragged OK (W rows clamped, stores guarded).
template <int OB>  // 1: bf16 output, 0: fp32 output
__global__ __launch_bounds__(256) void gemm_bt_mfma(
    const __hip_bfloat16* __restrict__ A, int lda,
    const __hip_bfloat16* __restrict__ W, int ldw,
    const float* __restrict__ bias,
    void* __restrict__ Cv, int ldc,
    int N, int K) {
    __shared__ __align__(16) __hip_bfloat16 As[128 * 32];
    __shared__ __align__(16) __hip_bfloat16 Ws[128 * 32];
    const int tid = threadIdx.x;
    const int lane = tid & 63;
    const int wave = tid >> 6;
    const int bm = blockIdx.y * 128;
    const int bn = blockIdx.x * 128;

    // staging: chunk c (0..511) -> row c>>2, k-offset (c&3)*8; this thread owns c=tid, c=tid+256
    const int r0 = tid >> 2;
    const int kk = (tid & 3) * 8;
    const __hip_bfloat16* gA0 = A + (size_t)(bm + r0) * lda + kk;
    const __hip_bfloat16* gA1 = gA0 + (size_t)64 * lda;
    int wrow0 = bn + r0;      if (wrow0 > N - 1) wrow0 = N - 1;
    int wrow1 = bn + r0 + 64; if (wrow1 > N - 1) wrow1 = N - 1;
    const __hip_bfloat16* gW0 = W + (size_t)wrow0 * ldw + kk;
    const __hip_bfloat16* gW1 = W + (size_t)wrow1 * ldw + kk;
    char* As_c = (char*)As + tid * 16;
    char* Ws_c = (char*)Ws + tid * 16;

    const int wr = wave >> 1, wc = wave & 1;
    const int fr = lane & 15, fq = lane >> 4;
    const __hip_bfloat16* Ard = &As[(wr * 64 + fr) * 32 + fq * 8];
    const __hip_bfloat16* Wrd = &Ws[(wc * 64 + fr) * 32 + fq * 8];

    f32x4 acc[4][4] = {};

    for (int k0 = 0; k0 < K; k0 += 32) {
        __syncthreads();   // prior reads done before overwrite
        GLL16(gA0 + k0, As_c);
        GLL16(gA1 + k0, As_c + 4096);
        GLL16(gW0 + k0, Ws_c);
        GLL16(gW1 + k0, Ws_c + 4096);
        __syncthreads();   // compiler drains vmcnt(0) before s_barrier -> LDS ready

        bf16x8 af[4], bg[4];
#pragma unroll
        for (int i = 0; i < 4; ++i) {
            af[i] = *reinterpret_cast<const bf16x8*>(Ard + i * 16 * 32);
            bg[i] = *reinterpret_cast<const bf16x8*>(Wrd + i * 16 * 32);
        }
#pragma unroll
        for (int mi = 0; mi < 4; ++mi)
#pragma unroll
            for (int ni = 0; ni < 4; ++ni)
                acc[mi][ni] = __builtin_amdgcn_mfma_f32_16x16x32_bf16(af[mi], bg[ni], acc[mi][ni], 0, 0, 0);
    }

    // epilogue: C/D layout col=lane&15, row=(lane>>4)*4+reg
#pragma unroll
    for (int ni = 0; ni < 4; ++ni) {
        const int col = bn + wc * 64 + ni * 16 + fr;
        if (col >= N) continue;
        const float bb = bias ? bias[col] : 0.0f;
#pragma unroll
        for (int mi = 0; mi < 4; ++mi) {
            const int row0 = bm + wr * 64 + mi * 16 + fq * 4;
#pragma unroll
            for (int r = 0; r < 4; ++r) {
                const float v = acc[mi][ni][r] + bb;
                if (OB)
                    reinterpret_cast<__hip_bfloat16*>(Cv)[(size_t)(row0 + r) * ldc + col] = __float2bfloat16(v);
                else
                    reinterpret_cast<float*>(Cv)[(size_t)(row0 + r) * ldc + col] = v;
            }
        }
    }
}

// ---------------- fp32 -> bf16 cast (strided rows) ----------------
__global__ __launch_bounds__(256) void cast_f32_to_bf16(
    const float* __restrict__ src, long long sstride, int cols,
    __hip_bfloat16* __restrict__ dst, int nrows) {
    const int c4n = cols >> 2;
    const long long total4 = (long long)nrows * c4n;
    for (long long i = (long long)blockIdx.x * 256 + threadIdx.x; i < total4;
         i += (long long)gridDim.x * 256) {
        const long long r = i / c4n;
        const int c = (int)(i - r * c4n) << 2;
        const float4 v = *reinterpret_cast<const float4*>(src + r * sstride + c);
        union { ushort4 u; __hip_bfloat16 h[4]; } o;
        o.h[0] = __float2bfloat16(v.x); o.h[1] = __float2bfloat16(v.y);
        o.h[2] = __float2bfloat16(v.z); o.h[3] = __float2bfloat16(v.w);
        *reinterpret_cast<ushort4*>(dst + r * (long long)cols + c) = o.u;
    }
}

// ---------------- attention: e-scores, softmax over S, context ----------------
// One block per batch row. 256 threads x 4 h-positions. enc/enc_proj in bf16, hproj/w2 fp32.
__global__ __launch_bounds__(256) void attn_ctx_kernel(
    const __hip_bfloat16* __restrict__ enc,
    const __hip_bfloat16* __restrict__ enc_proj,
    const float* __restrict__ hproj,   // includes b1
    const float* __restrict__ w2,
    float* __restrict__ ctx) {
    const int b = blockIdx.x;
    const int tid = threadIdx.x;
    const int lane = tid & 63, wave = tid >> 6;
    __shared__ float s_e[S_SZ];
    __shared__ float s_red[4];

    const float4 hp = reinterpret_cast<const float4*>(hproj + (size_t)b * H_SZ)[tid];
    const float4 w24 = reinterpret_cast<const float4*>(w2)[tid];
    const ushort4* ep_base = reinterpret_cast<const ushort4*>(enc_proj + (size_t)b * S_SZ * H_SZ);

    for (int s = 0; s < S_SZ; ++s) {
        ushort4 ep = ep_base[s * 256 + tid];
        float p = fast_tanh(bfraw2f(ep.x) + hp.x) * w24.x
                + fast_tanh(bfraw2f(ep.y) + hp.y) * w24.y
                + fast_tanh(bfraw2f(ep.z) + hp.z) * w24.z
                + fast_tanh(bfraw2f(ep.w) + hp.w) * w24.w;
#pragma unroll
        for (int off = 32; off > 0; off >>= 1) p += __shfl_down(p, off);
        if (lane == 0) s_red[wave] = p;
        __syncthreads();
        if (tid == 0) s_e[s] = s_red[0] + s_red[1] + s_red[2] + s_red[3];
        __syncthreads();
    }

    float m = -1e30f;
    for (int s = 0; s < S_SZ; ++s) m = fmaxf(m, s_e[s]);
    float sum = 0.f;
    for (int s = 0; s < S_SZ; ++s) sum += __expf(s_e[s] - m);
    const float inv = 1.0f / sum;

    const ushort4* enc_b = reinterpret_cast<const ushort4*>(enc + (size_t)b * S_SZ * H_SZ);
    float4 acc = make_float4(0.f, 0.f, 0.f, 0.f);
    for (int s = 0; s < S_SZ; ++s) {
        const float a = __expf(s_e[s] - m) * inv;
        ushort4 ev = enc_b[s * 256 + tid];
        acc.x += a * bfraw2f(ev.x); acc.y += a * bfraw2f(ev.y);
        acc.z += a * bfraw2f(ev.z); acc.w += a * bfraw2f(ev.w);
    }
    reinterpret_cast<float4*>(ctx + (size_t)b * H_SZ)[tid] = acc;
}

// ---------------- x_bf16[b] = [emb[it[b]] (512) | ctx[b] (1024)] ----------------
__global__ __launch_bounds__(256) void build_x_kernel(
    const float* __restrict__ emb,
    const int* __restrict__ targets,
    const float* __restrict__ ctx,
    __hip_bfloat16* __restrict__ x, int t) {
    const int b = blockIdx.x;
    const int tid = threadIdx.x;
    int it;
    if (t == 0) it = 0;
    else if (t == 1) it = targets[b] + 1;
    else it = targets[B_SZ + b] + 36;
    __hip_bfloat16* xr = x + (size_t)b * (DW_SZ + H_SZ);
    if (tid < DW_SZ / 4) {
        float4 v = reinterpret_cast<const float4*>(emb + (size_t)it * DW_SZ)[tid];
        union { ushort4 u; __hip_bfloat16 h[4]; } o;
        o.h[0] = __float2bfloat16(v.x); o.h[1] = __float2bfloat16(v.y);
        o.h[2] = __float2bfloat16(v.z); o.h[3] = __float2bfloat16(v.w);
        reinterpret_cast<ushort4*>(xr)[tid] = o.u;
    }
    {
        float4 v = reinterpret_cast<const float4*>(ctx + (size_t)b * H_SZ)[tid];
        union { ushort4 u; __hip_bfloat16 h[4]; } o;
        o.h[0] = __float2bfloat16(v.x); o.h[1] = __float2bfloat16(v.y);
        o.h[2] = __float2bfloat16(v.z); o.h[3] = __float2bfloat16(v.w);
        reinterpret_cast<ushort4*>(xr + DW_SZ)[tid] = o.u;
    }
}

// ---------------- GRU gate combine: h = (1-z)*n + z*h ----------------
__global__ __launch_bounds__(256) void gru_gate_kernel(
    const __hip_bfloat16* __restrict__ gi,
    const __hip_bfloat16* __restrict__ gh,
    float* __restrict__ h) {
    const int idx = blockIdx.x * 256 + threadIdx.x;   // over B*H
    const int b = idx >> 10;
    const int j = idx & 1023;
    const unsigned short* gib = reinterpret_cast<const unsigned short*>(gi) + (size_t)b * 3 * H_SZ;
    const unsigned short* ghb = reinterpret_cast<const unsigned short*>(gh) + (size_t)b * 3 * H_SZ;
    const float i_r = bfraw2f(gib[j]), i_z = bfraw2f(gib[H_SZ + j]), i_n = bfraw2f(gib[2 * H_SZ + j]);
    const float h_r = bfraw2f(ghb[j]), h_z = bfraw2f(ghb[H_SZ + j]), h_n = bfraw2f(ghb[2 * H_SZ + j]);
    const float r = fast_sigmoid(i_r + h_r);
    const float z = fast_sigmoid(i_z + h_z);
    const float n = fast_tanh(i_n + r * h_n);
    h[idx] = (1.0f - z) * n + z * h[idx];
}

// ---------------- in-place log-softmax over V per row ----------------
__global__ __launch_bounds__(256) void logsoftmax_kernel(float* __restrict__ buf) {
    const int b = blockIdx.x;
    const int tid = threadIdx.x;
    const int lane = tid & 63, wave = tid >> 6;
    __shared__ float s_red[4];
    __shared__ float s_bc;
    float* row = buf + (size_t)b * V_SZ;

    float m = -1e30f;
    for (int k = tid; k < V_SZ; k += 256) m = fmaxf(m, row[k]);
#pragma unroll
    for (int off = 32; off > 0; off >>= 1) m = fmaxf(m, __shfl_down(m, off));
    if (lane == 0) s_red[wave] = m;
    __syncthreads();
    if (tid == 0) s_bc = fmaxf(fmaxf(s_red[0], s_red[1]), fmaxf(s_red[2], s_red[3]));
    __syncthreads();
    m = s_bc;

    float sum = 0.f;
    for (int k = tid; k < V_SZ; k += 256) sum += expf(row[k] - m);
#pragma unroll
    for (int off = 32; off > 0; off >>= 1) sum += __shfl_down(sum, off);
    __syncthreads();
    if (lane == 0) s_red[wave] = sum;
    __syncthreads();
    if (tid == 0) s_bc = logf(s_red[0] + s_red[1] + s_red[2] + s_red[3]) + m;
    __syncthreads();
    const float ls = s_bc;

    for (int k = tid; k < V_SZ; k += 256) row[k] = row[k] - ls;
}

extern "C" void kernel_launch(void* const* d_in, const int* in_sizes, int n_in,
                              void* d_out, int out_size, void* d_ws, size_t ws_size,
                              hipStream_t stream) {
    const float* enc    = (const float*)d_in[0];
    const float* enc_h  = (const float*)d_in[1];
    const int*   tgt    = (const int*)d_in[2];
    const float* emb    = (const float*)d_in[3];
    const float* w1     = (const float*)d_in[4];
    const float* b1     = (const float*)d_in[5];
    const float* w2     = (const float*)d_in[6];
    const float* w_ih   = (const float*)d_in[7];
    const float* w_hh   = (const float*)d_in[8];
    const float* b_ih   = (const float*)d_in[9];
    const float* b_hh   = (const float*)d_in[10];
    const float* out0_w = (const float*)d_in[11];
    const float* out0_b = (const float*)d_in[12];
    const float* out1_w = (const float*)d_in[13];
    const float* out1_b = (const float*)d_in[14];
    float* out = (float*)d_out;

    char* wp = (char*)d_ws;
    auto carve = [&](size_t bytes) { char* p = wp; wp += (bytes + 255) & ~(size_t)255; return p; };
    __hip_bfloat16* enc_bf  = (__hip_bfloat16*)carve((size_t)B_SZ * S_SZ * H_SZ * 2);
    __hip_bfloat16* encp_bf = (__hip_bfloat16*)carve((size_t)B_SZ * S_SZ * H_SZ * 2);
    __hip_bfloat16* w1_bf   = (__hip_bfloat16*)carve((size_t)H_SZ * 2 * H_SZ * 2);
    __hip_bfloat16* wih_bf  = (__hip_bfloat16*)carve((size_t)3 * H_SZ * (DW_SZ + H_SZ) * 2);
    __hip_bfloat16* whh_bf  = (__hip_bfloat16*)carve((size_t)3 * H_SZ * H_SZ * 2);
    __hip_bfloat16* o0_bf   = (__hip_bfloat16*)carve((size_t)V_SZ * H_SZ * 2);
    __hip_bfloat16* o1_bf   = (__hip_bfloat16*)carve((size_t)V_SZ * H_SZ * 2);
    float*          h       = (float*)carve((size_t)B_SZ * H_SZ * 4);
    __hip_bfloat16* h_bf    = (__hip_bfloat16*)carve((size_t)B_SZ * H_SZ * 2);
    float*          hproj   = (float*)carve((size_t)B_SZ * H_SZ * 4);
    float*          ctx     = (float*)carve((size_t)B_SZ * H_SZ * 4);
    __hip_bfloat16* x_bf    = (__hip_bfloat16*)carve((size_t)B_SZ * (DW_SZ + H_SZ) * 2);
    __hip_bfloat16* gi_bf   = (__hip_bfloat16*)carve((size_t)B_SZ * 3 * H_SZ * 2);
    __hip_bfloat16* gh_bf   = (__hip_bfloat16*)carve((size_t)B_SZ * 3 * H_SZ * 2);

    // --- one-time casts ---
    cast_f32_to_bf16<<<2048, 256, 0, stream>>>(enc, H_SZ, H_SZ, enc_bf, B_SZ * S_SZ);
    cast_f32_to_bf16<<<256, 256, 0, stream>>>(w1, 2 * H_SZ, 2 * H_SZ, w1_bf, H_SZ);
    cast_f32_to_bf16<<<512, 256, 0, stream>>>(w_ih, DW_SZ + H_SZ, DW_SZ + H_SZ, wih_bf, 3 * H_SZ);
    cast_f32_to_bf16<<<384, 256, 0, stream>>>(w_hh, H_SZ, H_SZ, whh_bf, 3 * H_SZ);
    cast_f32_to_bf16<<<512, 256, 0, stream>>>(out0_w, H_SZ, H_SZ, o0_bf, V_SZ);
    cast_f32_to_bf16<<<512, 256, 0, stream>>>(out1_w, H_SZ, H_SZ, o1_bf, V_SZ);

    hipMemcpyAsync(h, enc_h, (size_t)B_SZ * H_SZ * sizeof(float), hipMemcpyDeviceToDevice, stream);
    cast_f32_to_bf16<<<256, 256, 0, stream>>>(h, H_SZ, H_SZ, h_bf, B_SZ);

    // enc_proj = enc @ w1[:, :H].T  (timestep-invariant), bf16 out
    gemm_bt_mfma<1><<<dim3(H_SZ / 128, (B_SZ * S_SZ) / 128), 256, 0, stream>>>(
        enc_bf, H_SZ, w1_bf, 2 * H_SZ, nullptr, encp_bf, H_SZ, H_SZ, H_SZ);

    for (int t = 0; t < 3; ++t) {
        // hproj = h @ w1[:, H:].T + b1   (fp32 out)
        gemm_bt_mfma<0><<<dim3(H_SZ / 128, B_SZ / 128), 256, 0, stream>>>(
            h_bf, H_SZ, w1_bf + H_SZ, 2 * H_SZ, b1, hproj, H_SZ, H_SZ, H_SZ);

        attn_ctx_kernel<<<B_SZ, 256, 0, stream>>>(enc_bf, encp_bf, hproj, w2, ctx);

        build_x_kernel<<<B_SZ, 256, 0, stream>>>(emb, tgt, ctx, x_bf, t);

        // gi = x @ w_ih.T + b_ih  (bf16 out)
        gemm_bt_mfma<1><<<dim3(3 * H_SZ / 128, B_SZ / 128), 256, 0, stream>>>(
            x_bf, DW_SZ + H_SZ, wih_bf, DW_SZ + H_SZ, b_ih, gi_bf, 3 * H_SZ, 3 * H_SZ, DW_SZ + H_SZ);
        // gh = h @ w_hh.T + b_hh  (bf16 out)
        gemm_bt_mfma<1><<<dim3(3 * H_SZ / 128, B_SZ / 128), 256, 0, stream>>>(
            h_bf, H_SZ, whh_bf, H_SZ, b_hh, gh_bf, 3 * H_SZ, 3 * H_SZ, H_SZ);

        gru_gate_kernel<<<(B_SZ * H_SZ) / 256, 256, 0, stream>>>(gi_bf, gh_bf, h);
        cast_f32_to_bf16<<<256, 256, 0, stream>>>(h, H_SZ, H_SZ, h_bf, B_SZ);

        // logits -> d_out[t] directly (fp32), then in-place log-softmax
        float* logits = out + (size_t)t * B_SZ * V_SZ;
        const __hip_bfloat16* ow = (t == 1) ? o1_bf : o0_bf;
        const float* ob = (t == 1) ? out1_b : out0_b;
        gemm_bt_mfma<0><<<dim3((V_SZ + 127) / 128, B_SZ / 128), 256, 0, stream>>>(
            h_bf, H_SZ, ow, H_SZ, ob, logits, V_SZ, V_SZ, H_SZ);

        logsoftmax_kernel<<<B_SZ, 256, 0, stream>>>(logits);
    }
}

// Round 3
// 693.502 us; speedup vs baseline: 5.7008x; 1.1424x over previous
//
#include <hip/hip_runtime.h>
#include <hip/hip_bf16.h>
#include <math.h>

#define B_SZ 1024
#define S_SZ 40
#define H_SZ 1024
#define DW_SZ 512
#define V_SZ 4000
#define XW (DW_SZ + H_SZ)      // 1536
#define NG (4 * H_SZ)          // 4096: [hproj | gh(3H)]

typedef __bf16 bf16x8 __attribute__((ext_vector_type(8)));
typedef float f32x4 __attribute__((ext_vector_type(4)));

__device__ __forceinline__ float fast_tanh(float x) {
    return 1.0f - 2.0f / (1.0f + __expf(2.0f * x));
}
__device__ __forceinline__ float fast_sigmoid(float x) {
    return 1.0f / (1.0f + __expf(-x));
}
__device__ __forceinline__ float bfraw2f(unsigned short u) {
    return __uint_as_float(((unsigned)u) << 16);
}
__device__ __forceinline__ unsigned short f2bfraw(float f) {
    __hip_bfloat16 h = __float2bfloat16(f);
    return *reinterpret_cast<unsigned short*>(&h);
}

#define GLL16(gp, lp)                                                                \
    __builtin_amdgcn_global_load_lds((const __attribute__((address_space(1))) void*)(gp), \
                                     (__attribute__((address_space(3))) void*)(lp), 16, 0, 0)

// ---------------- bf16 MFMA GEMM: C[m,n] = sum_k A[m,k]*W[n,k] + bias[n] ----------------
// 128x128 tile, BK=32, 256 threads (4 waves 2x2), wave does 64x64 via 4x4 frags of 16x16x32.
// 1-D grid; nbx = number of N-tiles. M multiple of 128. N ragged OK.
// SWZ=1: XCD-bijective remap (requires gridDim.x % 8 == 0) — use only for A-heavy GEMMs.
template <int OB, int SWZ>  // OB 1: bf16 out, 0: fp32 out
__global__ __launch_bounds__(256) void gemm_bt_mfma(
    const __hip_bfloat16* __restrict__ A, int lda,
    const __hip_bfloat16* __restrict__ W, int ldw,
    const float* __restrict__ bias,
    void* __restrict__ Cv, int ldc,
    int nbx, int N, int K) {
    __shared__ __align__(16) __hip_bfloat16 As[128 * 32];
    __shared__ __align__(16) __hip_bfloat16 Ws[128 * 32];
    const int tid = threadIdx.x;
    const int lane = tid & 63;
    const int wave = tid >> 6;

    int bid = blockIdx.x;
    if (SWZ) {
        const int cpx = gridDim.x >> 3;
        bid = (bid & 7) * cpx + (bid >> 3);
    }
    const int by = bid / nbx;
    const int bx = bid - by * nbx;
    const int bm = by * 128;
    const int bn = bx * 128;

    const int r0 = tid >> 2;
    const int kk = (tid & 3) * 8;
    const __hip_bfloat16* gA0 = A + (size_t)(bm + r0) * lda + kk;
    const __hip_bfloat16* gA1 = gA0 + (size_t)64 * lda;
    int wrow0 = bn + r0;      if (wrow0 > N - 1) wrow0 = N - 1;
    int wrow1 = bn + r0 + 64; if (wrow1 > N - 1) wrow1 = N - 1;
    const __hip_bfloat16* gW0 = W + (size_t)wrow0 * ldw + kk;
    const __hip_bfloat16* gW1 = W + (size_t)wrow1 * ldw + kk;
    char* As_c = (char*)As + tid * 16;
    char* Ws_c = (char*)Ws + tid * 16;

    const int wr = wave >> 1, wc = wave & 1;
    const int fr = lane & 15, fq = lane >> 4;
    const __hip_bfloat16* Ard = &As[(wr * 64 + fr) * 32 + fq * 8];
    const __hip_bfloat16* Wrd = &Ws[(wc * 64 + fr) * 32 + fq * 8];

    f32x4 acc[4][4] = {};

    for (int k0 = 0; k0 < K; k0 += 32) {
        __syncthreads();
        GLL16(gA0 + k0, As_c);
        GLL16(gA1 + k0, As_c + 4096);
        GLL16(gW0 + k0, Ws_c);
        GLL16(gW1 + k0, Ws_c + 4096);
        __syncthreads();

        bf16x8 af[4], bg[4];
#pragma unroll
        for (int i = 0; i < 4; ++i) {
            af[i] = *reinterpret_cast<const bf16x8*>(Ard + i * 16 * 32);
            bg[i] = *reinterpret_cast<const bf16x8*>(Wrd + i * 16 * 32);
        }
#pragma unroll
        for (int mi = 0; mi < 4; ++mi)
#pragma unroll
            for (int ni = 0; ni < 4; ++ni)
                acc[mi][ni] = __builtin_amdgcn_mfma_f32_16x16x32_bf16(af[mi], bg[ni], acc[mi][ni], 0, 0, 0);
    }

    // C/D layout: col = lane&15, row = (lane>>4)*4 + reg
#pragma unroll
    for (int ni = 0; ni < 4; ++ni) {
        const int col = bn + wc * 64 + ni * 16 + fr;
        if (col >= N) continue;
        const float bb = bias ? bias[col] : 0.0f;
#pragma unroll
        for (int mi = 0; mi < 4; ++mi) {
            const int row0 = bm + wr * 64 + mi * 16 + fq * 4;
#pragma unroll
            for (int r = 0; r < 4; ++r) {
                const float v = acc[mi][ni][r] + bb;
                if (OB)
                    reinterpret_cast<__hip_bfloat16*>(Cv)[(size_t)(row0 + r) * ldc + col] = __float2bfloat16(v);
                else
                    reinterpret_cast<float*>(Cv)[(size_t)(row0 + r) * ldc + col] = v;
            }
        }
    }
}

// ---------------- fp32 -> bf16 cast (strided rows) ----------------
__global__ __launch_bounds__(256) void cast_f32_to_bf16(
    const float* __restrict__ src, long long sstride, int cols,
    __hip_bfloat16* __restrict__ dst, int nrows) {
    const int c4n = cols >> 2;
    const long long total4 = (long long)nrows * c4n;
    for (long long i = (long long)blockIdx.x * 256 + threadIdx.x; i < total4;
         i += (long long)gridDim.x * 256) {
        const long long r = i / c4n;
        const int c = (int)(i - r * c4n) << 2;
        const float4 v = *reinterpret_cast<const float4*>(src + r * sstride + c);
        union { ushort4 u; __hip_bfloat16 h[4]; } o;
        o.h[0] = __float2bfloat16(v.x); o.h[1] = __float2bfloat16(v.y);
        o.h[2] = __float2bfloat16(v.z); o.h[3] = __float2bfloat16(v.w);
        *reinterpret_cast<ushort4*>(dst + r * (long long)cols + c) = o.u;
    }
}

// ---------------- bias_cat = [b1 | b_hh] ----------------
__global__ __launch_bounds__(256) void build_bias_cat(
    const float* __restrict__ b1, const float* __restrict__ b_hh,
    float* __restrict__ dst) {
    const int j = blockIdx.x * 256 + threadIdx.x;   // over 4096
    dst[j] = (j < H_SZ) ? b1[j] : b_hh[j - H_SZ];
}

// ---------------- prefill emb halves of x for all 3 steps ----------------
// grid 3*B blocks, 128 threads (512 floats / 4)
__global__ __launch_bounds__(128) void emb_prefill_kernel(
    const float* __restrict__ emb,
    const int* __restrict__ targets,
    __hip_bfloat16* __restrict__ x0,
    __hip_bfloat16* __restrict__ x1,
    __hip_bfloat16* __restrict__ x2) {
    const int blk = blockIdx.x;
    const int t = blk >> 10;
    const int b = blk & 1023;
    const int tid = threadIdx.x;
    int it;
    __hip_bfloat16* x;
    if (t == 0) { it = 0; x = x0; }
    else if (t == 1) { it = targets[b] + 1; x = x1; }
    else { it = targets[B_SZ + b] + 36; x = x2; }
    float4 v = reinterpret_cast<const float4*>(emb + (size_t)it * DW_SZ)[tid];
    union { ushort4 u; __hip_bfloat16 h[4]; } o;
    o.h[0] = __float2bfloat16(v.x); o.h[1] = __float2bfloat16(v.y);
    o.h[2] = __float2bfloat16(v.z); o.h[3] = __float2bfloat16(v.w);
    reinterpret_cast<ushort4*>(x + (size_t)b * XW)[tid] = o.u;
}

// ---------------- attention: scores, softmax over S, ctx -> bf16 into x[b, DW:] ----------------
// One block per batch row. 256 threads x 4 h-positions. hproj = hg_bf[b, 0:H] (bf16, includes b1).
__global__ __launch_bounds__(256) void attn_ctx_kernel(
    const __hip_bfloat16* __restrict__ enc,
    const __hip_bfloat16* __restrict__ enc_proj,
    const __hip_bfloat16* __restrict__ hg,     // [B][4096], first H = hproj
    const float* __restrict__ w2,
    __hip_bfloat16* __restrict__ x) {          // [B][XW], write at DW..
    const int b = blockIdx.x;
    const int tid = threadIdx.x;
    const int lane = tid & 63, wave = tid >> 6;
    __shared__ float s_e[S_SZ];
    __shared__ float s_red[4];

    const ushort4 hpu = reinterpret_cast<const ushort4*>(hg + (size_t)b * NG)[tid];
    const float hpx = bfraw2f(hpu.x), hpy = bfraw2f(hpu.y), hpz = bfraw2f(hpu.z), hpw = bfraw2f(hpu.w);
    const float4 w24 = reinterpret_cast<const float4*>(w2)[tid];
    const ushort4* ep_base = reinterpret_cast<const ushort4*>(enc_proj + (size_t)b * S_SZ * H_SZ);

    for (int s = 0; s < S_SZ; ++s) {
        ushort4 ep = ep_base[s * 256 + tid];
        float p = fast_tanh(bfraw2f(ep.x) + hpx) * w24.x
                + fast_tanh(bfraw2f(ep.y) + hpy) * w24.y
                + fast_tanh(bfraw2f(ep.z) + hpz) * w24.z
                + fast_tanh(bfraw2f(ep.w) + hpw) * w24.w;
#pragma unroll
        for (int off = 32; off > 0; off >>= 1) p += __shfl_down(p, off);
        if (lane == 0) s_red[wave] = p;
        __syncthreads();
        if (tid == 0) s_e[s] = s_red[0] + s_red[1] + s_red[2] + s_red[3];
        __syncthreads();
    }

    float m = -1e30f;
    for (int s = 0; s < S_SZ; ++s) m = fmaxf(m, s_e[s]);
    float sum = 0.f;
    for (int s = 0; s < S_SZ; ++s) sum += __expf(s_e[s] - m);
    const float inv = 1.0f / sum;

    const ushort4* enc_b = reinterpret_cast<const ushort4*>(enc + (size_t)b * S_SZ * H_SZ);
    float4 acc = make_float4(0.f, 0.f, 0.f, 0.f);
    for (int s = 0; s < S_SZ; ++s) {
        const float a = __expf(s_e[s] - m) * inv;
        ushort4 ev = enc_b[s * 256 + tid];
        acc.x += a * bfraw2f(ev.x); acc.y += a * bfraw2f(ev.y);
        acc.z += a * bfraw2f(ev.z); acc.w += a * bfraw2f(ev.w);
    }
    union { ushort4 u; __hip_bfloat16 h[4]; } o;
    o.h[0] = __float2bfloat16(acc.x); o.h[1] = __float2bfloat16(acc.y);
    o.h[2] = __float2bfloat16(acc.z); o.h[3] = __float2bfloat16(acc.w);
    reinterpret_cast<ushort4*>(x + (size_t)b * XW + DW_SZ)[tid] = o.u;
}

// ---------------- GRU gate combine: h = (1-z)*n + z*h; also h_bf ----------------
__global__ __launch_bounds__(256) void gru_gate_kernel(
    const __hip_bfloat16* __restrict__ gi,   // [B][3H]
    const __hip_bfloat16* __restrict__ hg,   // [B][4H], gh at +H
    float* __restrict__ h,
    __hip_bfloat16* __restrict__ h_bf) {
    const int idx = blockIdx.x * 256 + threadIdx.x;   // over B*H
    const int b = idx >> 10;
    const int j = idx & 1023;
    const unsigned short* gib = reinterpret_cast<const unsigned short*>(gi) + (size_t)b * 3 * H_SZ;
    const unsigned short* ghb = reinterpret_cast<const unsigned short*>(hg) + (size_t)b * NG + H_SZ;
    const float i_r = bfraw2f(gib[j]), i_z = bfraw2f(gib[H_SZ + j]), i_n = bfraw2f(gib[2 * H_SZ + j]);
    const float h_r = bfraw2f(ghb[j]), h_z = bfraw2f(ghb[H_SZ + j]), h_n = bfraw2f(ghb[2 * H_SZ + j]);
    const float r = fast_sigmoid(i_r + h_r);
    const float z = fast_sigmoid(i_z + h_z);
    const float n = fast_tanh(i_n + r * h_n);
    const float hv = (1.0f - z) * n + z * h[idx];
    h[idx] = hv;
    h_bf[idx] = __float2bfloat16(hv);
}

// ---------------- in-place log-softmax over V per row ----------------
__global__ __launch_bounds__(256) void logsoftmax_kernel(float* __restrict__ buf) {
    const int b = blockIdx.x;
    const int tid = threadIdx.x;
    const int lane = tid & 63, wave = tid >> 6;
    __shared__ float s_red[4];
    __shared__ float s_bc;
    float* row = buf + (size_t)b * V_SZ;

    float m = -1e30f;
    for (int k = tid; k < V_SZ; k += 256) m = fmaxf(m, row[k]);
#pragma unroll
    for (int off = 32; off > 0; off >>= 1) m = fmaxf(m, __shfl_down(m, off));
    if (lane == 0) s_red[wave] = m;
    __syncthreads();
    if (tid == 0) s_bc = fmaxf(fmaxf(s_red[0], s_red[1]), fmaxf(s_red[2], s_red[3]));
    __syncthreads();
    m = s_bc;

    float sum = 0.f;
    for (int k = tid; k < V_SZ; k += 256) sum += expf(row[k] - m);
#pragma unroll
    for (int off = 32; off > 0; off >>= 1) sum += __shfl_down(sum, off);
    __syncthreads();
    if (lane == 0) s_red[wave] = sum;
    __syncthreads();
    if (tid == 0) s_bc = logf(s_red[0] + s_red[1] + s_red[2] + s_red[3]) + m;
    __syncthreads();
    const float ls = s_bc;

    for (int k = tid; k < V_SZ; k += 256) row[k] = row[k] - ls;
}

extern "C" void kernel_launch(void* const* d_in, const int* in_sizes, int n_in,
                              void* d_out, int out_size, void* d_ws, size_t ws_size,
                              hipStream_t stream) {
    const float* enc    = (const float*)d_in[0];
    const float* enc_h  = (const float*)d_in[1];
    const int*   tgt    = (const int*)d_in[2];
    const float* emb    = (const float*)d_in[3];
    const float* w1     = (const float*)d_in[4];
    const float* b1     = (const float*)d_in[5];
    const float* w2     = (const float*)d_in[6];
    const float* w_ih   = (const float*)d_in[7];
    const float* w_hh   = (const float*)d_in[8];
    const float* b_ih   = (const float*)d_in[9];
    const float* b_hh   = (const float*)d_in[10];
    const float* out0_w = (const float*)d_in[11];
    const float* out0_b = (const float*)d_in[12];
    const float* out1_w = (const float*)d_in[13];
    const float* out1_b = (const float*)d_in[14];
    float* out = (float*)d_out;

    char* wp = (char*)d_ws;
    auto carve = [&](size_t bytes) { char* p = wp; wp += (bytes + 255) & ~(size_t)255; return p; };
    __hip_bfloat16* enc_bf  = (__hip_bfloat16*)carve((size_t)B_SZ * S_SZ * H_SZ * 2);
    __hip_bfloat16* encp_bf = (__hip_bfloat16*)carve((size_t)B_SZ * S_SZ * H_SZ * 2);
    __hip_bfloat16* w1a_bf  = (__hip_bfloat16*)carve((size_t)H_SZ * H_SZ * 2);        // w1[:, :H]
    __hip_bfloat16* wcat_bf = (__hip_bfloat16*)carve((size_t)NG * H_SZ * 2);          // [w1[:,H:] ; w_hh]
    __hip_bfloat16* wih_bf  = (__hip_bfloat16*)carve((size_t)3 * H_SZ * XW * 2);
    __hip_bfloat16* o0_bf   = (__hip_bfloat16*)carve((size_t)V_SZ * H_SZ * 2);
    __hip_bfloat16* o1_bf   = (__hip_bfloat16*)carve((size_t)V_SZ * H_SZ * 2);
    float*          bias_cat= (float*)carve((size_t)NG * 4);
    float*          h       = (float*)carve((size_t)B_SZ * H_SZ * 4);
    __hip_bfloat16* h_bf    = (__hip_bfloat16*)carve((size_t)B_SZ * H_SZ * 2);
    __hip_bfloat16* hg_bf   = (__hip_bfloat16*)carve((size_t)B_SZ * NG * 2);          // [hproj|gh]
    __hip_bfloat16* x_bf[3];
    for (int t = 0; t < 3; ++t) x_bf[t] = (__hip_bfloat16*)carve((size_t)B_SZ * XW * 2);
    __hip_bfloat16* gi_bf   = (__hip_bfloat16*)carve((size_t)B_SZ * 3 * H_SZ * 2);

    // --- one-time prep ---
    cast_f32_to_bf16<<<2048, 256, 0, stream>>>(enc, H_SZ, H_SZ, enc_bf, B_SZ * S_SZ);
    cast_f32_to_bf16<<<128, 256, 0, stream>>>(w1, 2 * H_SZ, H_SZ, w1a_bf, H_SZ);                   // enc part
    cast_f32_to_bf16<<<128, 256, 0, stream>>>(w1 + H_SZ, 2 * H_SZ, H_SZ, wcat_bf, H_SZ);           // h part
    cast_f32_to_bf16<<<384, 256, 0, stream>>>(w_hh, H_SZ, H_SZ, wcat_bf + (size_t)H_SZ * H_SZ, 3 * H_SZ);
    cast_f32_to_bf16<<<512, 256, 0, stream>>>(w_ih, XW, XW, wih_bf, 3 * H_SZ);
    cast_f32_to_bf16<<<512, 256, 0, stream>>>(out0_w, H_SZ, H_SZ, o0_bf, V_SZ);
    cast_f32_to_bf16<<<512, 256, 0, stream>>>(out1_w, H_SZ, H_SZ, o1_bf, V_SZ);
    build_bias_cat<<<NG / 256, 256, 0, stream>>>(b1, b_hh, bias_cat);
    emb_prefill_kernel<<<3 * B_SZ, 128, 0, stream>>>(emb, tgt, x_bf[0], x_bf[1], x_bf[2]);

    hipMemcpyAsync(h, enc_h, (size_t)B_SZ * H_SZ * sizeof(float), hipMemcpyDeviceToDevice, stream);
    cast_f32_to_bf16<<<256, 256, 0, stream>>>(h, H_SZ, H_SZ, h_bf, B_SZ);

    // enc_proj = enc @ w1[:, :H].T  (timestep-invariant, bf16 out, XCD-swizzled: A-heavy)
    gemm_bt_mfma<1, 1><<<(B_SZ * S_SZ / 128) * (H_SZ / 128), 256, 0, stream>>>(
        enc_bf, H_SZ, w1a_bf, H_SZ, nullptr, encp_bf, H_SZ, H_SZ / 128, H_SZ, H_SZ);

    for (int t = 0; t < 3; ++t) {
        // [hproj | gh] = h @ [w1_h | w_hh].T + [b1 | b_hh]   (bf16 out, N=4096)
        gemm_bt_mfma<1, 0><<<(B_SZ / 128) * (NG / 128), 256, 0, stream>>>(
            h_bf, H_SZ, wcat_bf, H_SZ, bias_cat, hg_bf, NG, NG / 128, NG, H_SZ);

        attn_ctx_kernel<<<B_SZ, 256, 0, stream>>>(enc_bf, encp_bf, hg_bf, w2, x_bf[t]);

        // gi = x @ w_ih.T + b_ih  (bf16 out)
        gemm_bt_mfma<1, 0><<<(B_SZ / 128) * (3 * H_SZ / 128), 256, 0, stream>>>(
            x_bf[t], XW, wih_bf, XW, b_ih, gi_bf, 3 * H_SZ, 3 * H_SZ / 128, 3 * H_SZ, XW);

        gru_gate_kernel<<<(B_SZ * H_SZ) / 256, 256, 0, stream>>>(gi_bf, hg_bf, h, h_bf);

        // logits -> d_out[t] (fp32), then in-place log-softmax
        float* logits = out + (size_t)t * B_SZ * V_SZ;
        const __hip_bfloat16* ow = (t == 1) ? o1_bf : o0_bf;
        const float* ob = (t == 1) ? out1_b : out0_b;
        gemm_bt_mfma<0, 0><<<(B_SZ / 128) * ((V_SZ + 127) / 128), 256, 0, stream>>>(
            h_bf, H_SZ, ow, H_SZ, ob, logits, V_SZ, (V_SZ + 127) / 128, V_SZ, H_SZ);

        logsoftmax_kernel<<<B_SZ, 256, 0, stream>>>(logits);
    }
}

// Round 4
// 595.870 us; speedup vs baseline: 6.6348x; 1.1638x over previous
//
#include <hip/hip_runtime.h>
#include <hip/hip_bf16.h>
#include <math.h>

#define B_SZ 1024
#define S_SZ 40
#define H_SZ 1024
#define DW_SZ 512
#define V_SZ 4000
#define XW (DW_SZ + H_SZ)      // 1536
#define NG (4 * H_SZ)          // 4096: [hproj | gh(3H)]

typedef __bf16 bf16x8 __attribute__((ext_vector_type(8)));
typedef float f32x4 __attribute__((ext_vector_type(4)));

__device__ __forceinline__ float fast_tanh(float x) {
    return 1.0f - 2.0f / (1.0f + __expf(2.0f * x));
}
__device__ __forceinline__ float fast_sigmoid(float x) {
    return 1.0f / (1.0f + __expf(-x));
}
__device__ __forceinline__ float bfraw2f(unsigned short u) {
    return __uint_as_float(((unsigned)u) << 16);
}

#define GLL16(gp, lp)                                                                \
    __builtin_amdgcn_global_load_lds((const __attribute__((address_space(1))) void*)(gp), \
                                     (__attribute__((address_space(3))) void*)(lp), 16, 0, 0)

// ---------------- bf16 MFMA GEMM: C[m,n] = sum_k A[m,k]*W[n,k] + bias[n] ----------------
template <int OB, int SWZ>  // OB 1: bf16 out, 0: fp32 out
__global__ __launch_bounds__(256) void gemm_bt_mfma(
    const __hip_bfloat16* __restrict__ A, int lda,
    const __hip_bfloat16* __restrict__ W, int ldw,
    const float* __restrict__ bias,
    void* __restrict__ Cv, int ldc,
    int nbx, int N, int K) {
    __shared__ __align__(16) __hip_bfloat16 As[128 * 32];
    __shared__ __align__(16) __hip_bfloat16 Ws[128 * 32];
    const int tid = threadIdx.x;
    const int lane = tid & 63;
    const int wave = tid >> 6;

    int bid = blockIdx.x;
    if (SWZ) {
        const int cpx = gridDim.x >> 3;
        bid = (bid & 7) * cpx + (bid >> 3);
    }
    const int by = bid / nbx;
    const int bx = bid - by * nbx;
    const int bm = by * 128;
    const int bn = bx * 128;

    const int r0 = tid >> 2;
    const int kk = (tid & 3) * 8;
    const __hip_bfloat16* gA0 = A + (size_t)(bm + r0) * lda + kk;
    const __hip_bfloat16* gA1 = gA0 + (size_t)64 * lda;
    int wrow0 = bn + r0;      if (wrow0 > N - 1) wrow0 = N - 1;
    int wrow1 = bn + r0 + 64; if (wrow1 > N - 1) wrow1 = N - 1;
    const __hip_bfloat16* gW0 = W + (size_t)wrow0 * ldw + kk;
    const __hip_bfloat16* gW1 = W + (size_t)wrow1 * ldw + kk;
    char* As_c = (char*)As + tid * 16;
    char* Ws_c = (char*)Ws + tid * 16;

    const int wr = wave >> 1, wc = wave & 1;
    const int fr = lane & 15, fq = lane >> 4;
    const __hip_bfloat16* Ard = &As[(wr * 64 + fr) * 32 + fq * 8];
    const __hip_bfloat16* Wrd = &Ws[(wc * 64 + fr) * 32 + fq * 8];

    f32x4 acc[4][4] = {};

    for (int k0 = 0; k0 < K; k0 += 32) {
        __syncthreads();
        GLL16(gA0 + k0, As_c);
        GLL16(gA1 + k0, As_c + 4096);
        GLL16(gW0 + k0, Ws_c);
        GLL16(gW1 + k0, Ws_c + 4096);
        __syncthreads();

        bf16x8 af[4], bg[4];
#pragma unroll
        for (int i = 0; i < 4; ++i) {
            af[i] = *reinterpret_cast<const bf16x8*>(Ard + i * 16 * 32);
            bg[i] = *reinterpret_cast<const bf16x8*>(Wrd + i * 16 * 32);
        }
#pragma unroll
        for (int mi = 0; mi < 4; ++mi)
#pragma unroll
            for (int ni = 0; ni < 4; ++ni)
                acc[mi][ni] = __builtin_amdgcn_mfma_f32_16x16x32_bf16(af[mi], bg[ni], acc[mi][ni], 0, 0, 0);
    }

    // C/D layout: col = lane&15, row = (lane>>4)*4 + reg
#pragma unroll
    for (int ni = 0; ni < 4; ++ni) {
        const int col = bn + wc * 64 + ni * 16 + fr;
        if (col >= N) continue;
        const float bb = bias ? bias[col] : 0.0f;
#pragma unroll
        for (int mi = 0; mi < 4; ++mi) {
            const int row0 = bm + wr * 64 + mi * 16 + fq * 4;
#pragma unroll
            for (int r = 0; r < 4; ++r) {
                const float v = acc[mi][ni][r] + bb;
                if (OB)
                    reinterpret_cast<__hip_bfloat16*>(Cv)[(size_t)(row0 + r) * ldc + col] = __float2bfloat16(v);
                else
                    reinterpret_cast<float*>(Cv)[(size_t)(row0 + r) * ldc + col] = v;
            }
        }
    }
}

// ---------------- dual GEMM: cols [0,4096) -> hg (bf16, +bias_cat); cols [4096,4096+V) -> logits (fp32, +ob)
// A = h_bf [B][H]. nbx = 64 (32 hg tiles + 32 logit tiles). full==0 skips hg half.
__global__ __launch_bounds__(256) void gemm_dual_mfma(
    const __hip_bfloat16* __restrict__ A,
    const __hip_bfloat16* __restrict__ Wg,   // wcat [4096][1024]
    const __hip_bfloat16* __restrict__ Wo,   // out*_w [4000][1024]
    const float* __restrict__ bias_cat,
    const float* __restrict__ ob,
    __hip_bfloat16* __restrict__ hg,
    float* __restrict__ logits,
    int full) {
    const int nbx = 64;
    const int bid = blockIdx.x;
    const int by = bid / nbx;
    const int bx = bid - by * nbx;
    const int bm = by * 128;
    const int bn = bx * 128;
    const int is_hg = (bn < NG);
    if (!full && is_hg) return;

    __shared__ __align__(16) __hip_bfloat16 As[128 * 32];
    __shared__ __align__(16) __hip_bfloat16 Ws[128 * 32];
    const int tid = threadIdx.x;
    const int lane = tid & 63;
    const int wave = tid >> 6;

    const __hip_bfloat16* Wb = is_hg ? Wg : Wo;
    const int coff = is_hg ? bn : bn - NG;
    const int nn = is_hg ? NG : V_SZ;

    const int r0 = tid >> 2;
    const int kk = (tid & 3) * 8;
    const __hip_bfloat16* gA0 = A + (size_t)(bm + r0) * H_SZ + kk;
    const __hip_bfloat16* gA1 = gA0 + (size_t)64 * H_SZ;
    int wrow0 = coff + r0;      if (wrow0 > nn - 1) wrow0 = nn - 1;
    int wrow1 = coff + r0 + 64; if (wrow1 > nn - 1) wrow1 = nn - 1;
    const __hip_bfloat16* gW0 = Wb + (size_t)wrow0 * H_SZ + kk;
    const __hip_bfloat16* gW1 = Wb + (size_t)wrow1 * H_SZ + kk;
    char* As_c = (char*)As + tid * 16;
    char* Ws_c = (char*)Ws + tid * 16;

    const int wr = wave >> 1, wc = wave & 1;
    const int fr = lane & 15, fq = lane >> 4;
    const __hip_bfloat16* Ard = &As[(wr * 64 + fr) * 32 + fq * 8];
    const __hip_bfloat16* Wrd = &Ws[(wc * 64 + fr) * 32 + fq * 8];

    f32x4 acc[4][4] = {};

    for (int k0 = 0; k0 < H_SZ; k0 += 32) {
        __syncthreads();
        GLL16(gA0 + k0, As_c);
        GLL16(gA1 + k0, As_c + 4096);
        GLL16(gW0 + k0, Ws_c);
        GLL16(gW1 + k0, Ws_c + 4096);
        __syncthreads();

        bf16x8 af[4], bg[4];
#pragma unroll
        for (int i = 0; i < 4; ++i) {
            af[i] = *reinterpret_cast<const bf16x8*>(Ard + i * 16 * 32);
            bg[i] = *reinterpret_cast<const bf16x8*>(Wrd + i * 16 * 32);
        }
#pragma unroll
        for (int mi = 0; mi < 4; ++mi)
#pragma unroll
            for (int ni = 0; ni < 4; ++ni)
                acc[mi][ni] = __builtin_amdgcn_mfma_f32_16x16x32_bf16(af[mi], bg[ni], acc[mi][ni], 0, 0, 0);
    }

#pragma unroll
    for (int ni = 0; ni < 4; ++ni) {
        const int cl = coff + wc * 64 + ni * 16 + fr;
        if (cl >= nn) continue;
        const float bb = is_hg ? bias_cat[cl] : ob[cl];
#pragma unroll
        for (int mi = 0; mi < 4; ++mi) {
            const int row0 = bm + wr * 64 + mi * 16 + fq * 4;
#pragma unroll
            for (int r = 0; r < 4; ++r) {
                const float v = acc[mi][ni][r] + bb;
                if (is_hg)
                    hg[(size_t)(row0 + r) * NG + cl] = __float2bfloat16(v);
                else
                    logits[(size_t)(row0 + r) * V_SZ + cl] = v;
            }
        }
    }
}

// ---------------- fp32 -> bf16 cast (strided rows) ----------------
__global__ __launch_bounds__(256) void cast_f32_to_bf16(
    const float* __restrict__ src, long long sstride, int cols,
    __hip_bfloat16* __restrict__ dst, int nrows) {
    const int c4n = cols >> 2;
    const long long total4 = (long long)nrows * c4n;
    for (long long i = (long long)blockIdx.x * 256 + threadIdx.x; i < total4;
         i += (long long)gridDim.x * 256) {
        const long long r = i / c4n;
        const int c = (int)(i - r * c4n) << 2;
        const float4 v = *reinterpret_cast<const float4*>(src + r * sstride + c);
        union { ushort4 u; __hip_bfloat16 h[4]; } o;
        o.h[0] = __float2bfloat16(v.x); o.h[1] = __float2bfloat16(v.y);
        o.h[2] = __float2bfloat16(v.z); o.h[3] = __float2bfloat16(v.w);
        *reinterpret_cast<ushort4*>(dst + r * (long long)cols + c) = o.u;
    }
}

// ---------------- unified weight cast: all 6 weight segments in one launch ----------------
struct CastSeg { const float* src; long long sstride; int c4n; __hip_bfloat16* dst; long long n4; };
__global__ __launch_bounds__(256) void cast_all_kernel(CastSeg s0, CastSeg s1, CastSeg s2,
                                                       CastSeg s3, CastSeg s4, CastSeg s5) {
    const long long e0 = s0.n4, e1 = e0 + s1.n4, e2 = e1 + s2.n4,
                    e3 = e2 + s3.n4, e4 = e3 + s4.n4, e5 = e4 + s5.n4;
    for (long long i = (long long)blockIdx.x * 256 + threadIdx.x; i < e5;
         i += (long long)gridDim.x * 256) {
        CastSeg sg; long long li = i;
        if (i < e0) { sg = s0; }
        else if (i < e1) { sg = s1; li -= e0; }
        else if (i < e2) { sg = s2; li -= e1; }
        else if (i < e3) { sg = s3; li -= e2; }
        else if (i < e4) { sg = s4; li -= e3; }
        else { sg = s5; li -= e4; }
        const long long r = li / sg.c4n;
        const int c = (int)(li - r * sg.c4n) << 2;
        const float4 v = *reinterpret_cast<const float4*>(sg.src + r * sg.sstride + c);
        union { ushort4 u; __hip_bfloat16 h[4]; } o;
        o.h[0] = __float2bfloat16(v.x); o.h[1] = __float2bfloat16(v.y);
        o.h[2] = __float2bfloat16(v.z); o.h[3] = __float2bfloat16(v.w);
        *reinterpret_cast<ushort4*>(sg.dst + r * (long long)(sg.c4n << 2) + c) = o.u;
    }
}

// ---------------- bias_cat = [b1 | b_hh] ----------------
__global__ __launch_bounds__(256) void build_bias_cat(
    const float* __restrict__ b1, const float* __restrict__ b_hh,
    float* __restrict__ dst) {
    const int j = blockIdx.x * 256 + threadIdx.x;
    dst[j] = (j < H_SZ) ? b1[j] : b_hh[j - H_SZ];
}

// ---------------- h init: h = enc_h (f32) and h_bf ----------------
__global__ __launch_bounds__(256) void h_init_kernel(
    const float* __restrict__ enc_h, float* __restrict__ h, __hip_bfloat16* __restrict__ h_bf) {
    const int i = blockIdx.x * 256 + threadIdx.x;   // over B*H/4
    const float4 v = reinterpret_cast<const float4*>(enc_h)[i];
    reinterpret_cast<float4*>(h)[i] = v;
    union { ushort4 u; __hip_bfloat16 hh[4]; } o;
    o.hh[0] = __float2bfloat16(v.x); o.hh[1] = __float2bfloat16(v.y);
    o.hh[2] = __float2bfloat16(v.z); o.hh[3] = __float2bfloat16(v.w);
    reinterpret_cast<ushort4*>(h_bf)[i] = o.u;
}

// ---------------- prefill emb halves of x for all 3 steps ----------------
__global__ __launch_bounds__(128) void emb_prefill_kernel(
    const float* __restrict__ emb,
    const int* __restrict__ targets,
    __hip_bfloat16* __restrict__ x0,
    __hip_bfloat16* __restrict__ x1,
    __hip_bfloat16* __restrict__ x2) {
    const int blk = blockIdx.x;
    const int t = blk >> 10;
    const int b = blk & 1023;
    const int tid = threadIdx.x;
    int it;
    __hip_bfloat16* x;
    if (t == 0) { it = 0; x = x0; }
    else if (t == 1) { it = targets[b] + 1; x = x1; }
    else { it = targets[B_SZ + b] + 36; x = x2; }
    float4 v = reinterpret_cast<const float4*>(emb + (size_t)it * DW_SZ)[tid];
    union { ushort4 u; __hip_bfloat16 h[4]; } o;
    o.h[0] = __float2bfloat16(v.x); o.h[1] = __float2bfloat16(v.y);
    o.h[2] = __float2bfloat16(v.z); o.h[3] = __float2bfloat16(v.w);
    reinterpret_cast<ushort4*>(x + (size_t)b * XW)[tid] = o.u;
}

// ---------------- attention (wave-parallel scores): block = one b, 4 waves ----------------
// Phase 1: wave w computes s = w+4i (i<10): 64 lanes x 16 elems; wave shfl reduce; 1 barrier.
// Phase 2: softmax over s_e[40] per thread; ctx accumulate; bf16 write into x[b, DW:].
__global__ __launch_bounds__(256) void attn_ctx_kernel(
    const __hip_bfloat16* __restrict__ enc,
    const __hip_bfloat16* __restrict__ enc_proj,
    const __hip_bfloat16* __restrict__ hg,     // [B][4096], first H = hproj (incl b1)
    const float* __restrict__ w2,
    __hip_bfloat16* __restrict__ x) {          // [B][XW], write at DW..
    const int b = blockIdx.x;
    const int tid = threadIdx.x;
    const int lane = tid & 63, wave = tid >> 6;
    __shared__ float s_e[S_SZ];

    // preload hproj & w2 at this lane's 16 positions: idx = p*256 + lane*4 + q
    float hp[16], wv[16];
    const unsigned short* hgrow = reinterpret_cast<const unsigned short*>(hg) + (size_t)b * NG;
#pragma unroll
    for (int p = 0; p < 4; ++p) {
        const int base = p * 256 + lane * 4;
        ushort4 hu = *reinterpret_cast<const ushort4*>(hgrow + base);
        float4 wq = *reinterpret_cast<const float4*>(w2 + base);
        hp[p * 4 + 0] = bfraw2f(hu.x); hp[p * 4 + 1] = bfraw2f(hu.y);
        hp[p * 4 + 2] = bfraw2f(hu.z); hp[p * 4 + 3] = bfraw2f(hu.w);
        wv[p * 4 + 0] = wq.x; wv[p * 4 + 1] = wq.y;
        wv[p * 4 + 2] = wq.z; wv[p * 4 + 3] = wq.w;
    }

    const unsigned short* ep0 = reinterpret_cast<const unsigned short*>(enc_proj) + (size_t)b * S_SZ * H_SZ;
#pragma unroll 2
    for (int i = 0; i < 10; ++i) {
        const int s = wave + 4 * i;
        const unsigned short* row = ep0 + (size_t)s * H_SZ;
        float acc = 0.f;
#pragma unroll
        for (int p = 0; p < 4; ++p) {
            ushort4 eu = *reinterpret_cast<const ushort4*>(row + p * 256 + lane * 4);
            acc += fast_tanh(bfraw2f(eu.x) + hp[p * 4 + 0]) * wv[p * 4 + 0]
                 + fast_tanh(bfraw2f(eu.y) + hp[p * 4 + 1]) * wv[p * 4 + 1]
                 + fast_tanh(bfraw2f(eu.z) + hp[p * 4 + 2]) * wv[p * 4 + 2]
                 + fast_tanh(bfraw2f(eu.w) + hp[p * 4 + 3]) * wv[p * 4 + 3];
        }
#pragma unroll
        for (int off = 32; off > 0; off >>= 1) acc += __shfl_down(acc, off);
        if (lane == 0) s_e[s] = acc;
    }
    __syncthreads();

    float m = -1e30f;
    for (int s = 0; s < S_SZ; ++s) m = fmaxf(m, s_e[s]);
    float sum = 0.f;
    for (int s = 0; s < S_SZ; ++s) sum += __expf(s_e[s] - m);
    const float inv = 1.0f / sum;

    const ushort4* enc_b = reinterpret_cast<const ushort4*>(enc + (size_t)b * S_SZ * H_SZ);
    float4 acc = make_float4(0.f, 0.f, 0.f, 0.f);
    for (int s = 0; s < S_SZ; ++s) {
        const float a = __expf(s_e[s] - m) * inv;
        ushort4 ev = enc_b[s * 256 + tid];
        acc.x += a * bfraw2f(ev.x); acc.y += a * bfraw2f(ev.y);
        acc.z += a * bfraw2f(ev.z); acc.w += a * bfraw2f(ev.w);
    }
    union { ushort4 u; __hip_bfloat16 h[4]; } o;
    o.h[0] = __float2bfloat16(acc.x); o.h[1] = __float2bfloat16(acc.y);
    o.h[2] = __float2bfloat16(acc.z); o.h[3] = __float2bfloat16(acc.w);
    reinterpret_cast<ushort4*>(x + (size_t)b * XW + DW_SZ)[tid] = o.u;
}

// ---------------- GRU gate combine: h = (1-z)*n + z*h; also h_bf ----------------
__global__ __launch_bounds__(256) void gru_gate_kernel(
    const __hip_bfloat16* __restrict__ gi,   // [B][3H]
    const __hip_bfloat16* __restrict__ hg,   // [B][4H], gh at +H
    float* __restrict__ h,
    __hip_bfloat16* __restrict__ h_bf) {
    const int idx = blockIdx.x * 256 + threadIdx.x;   // over B*H
    const int b = idx >> 10;
    const int j = idx & 1023;
    const unsigned short* gib = reinterpret_cast<const unsigned short*>(gi) + (size_t)b * 3 * H_SZ;
    const unsigned short* ghb = reinterpret_cast<const unsigned short*>(hg) + (size_t)b * NG + H_SZ;
    const float i_r = bfraw2f(gib[j]), i_z = bfraw2f(gib[H_SZ + j]), i_n = bfraw2f(gib[2 * H_SZ + j]);
    const float h_r = bfraw2f(ghb[j]), h_z = bfraw2f(ghb[H_SZ + j]), h_n = bfraw2f(ghb[2 * H_SZ + j]);
    const float r = fast_sigmoid(i_r + h_r);
    const float z = fast_sigmoid(i_z + h_z);
    const float n = fast_tanh(i_n + r * h_n);
    const float hv = (1.0f - z) * n + z * h[idx];
    h[idx] = hv;
    h_bf[idx] = __float2bfloat16(hv);
}

// ---------------- in-place log-softmax over V per row ----------------
__global__ __launch_bounds__(256) void logsoftmax_kernel(float* __restrict__ buf) {
    const int b = blockIdx.x;
    const int tid = threadIdx.x;
    const int lane = tid & 63, wave = tid >> 6;
    __shared__ float s_red[4];
    __shared__ float s_bc;
    float* row = buf + (size_t)b * V_SZ;

    float m = -1e30f;
    for (int k = tid; k < V_SZ; k += 256) m = fmaxf(m, row[k]);
#pragma unroll
    for (int off = 32; off > 0; off >>= 1) m = fmaxf(m, __shfl_down(m, off));
    if (lane == 0) s_red[wave] = m;
    __syncthreads();
    if (tid == 0) s_bc = fmaxf(fmaxf(s_red[0], s_red[1]), fmaxf(s_red[2], s_red[3]));
    __syncthreads();
    m = s_bc;

    float sum = 0.f;
    for (int k = tid; k < V_SZ; k += 256) sum += expf(row[k] - m);
#pragma unroll
    for (int off = 32; off > 0; off >>= 1) sum += __shfl_down(sum, off);
    __syncthreads();
    if (lane == 0) s_red[wave] = sum;
    __syncthreads();
    if (tid == 0) s_bc = logf(s_red[0] + s_red[1] + s_red[2] + s_red[3]) + m;
    __syncthreads();
    const float ls = s_bc;

    for (int k = tid; k < V_SZ; k += 256) row[k] = row[k] - ls;
}

extern "C" void kernel_launch(void* const* d_in, const int* in_sizes, int n_in,
                              void* d_out, int out_size, void* d_ws, size_t ws_size,
                              hipStream_t stream) {
    const float* enc    = (const float*)d_in[0];
    const float* enc_h  = (const float*)d_in[1];
    const int*   tgt    = (const int*)d_in[2];
    const float* emb    = (const float*)d_in[3];
    const float* w1     = (const float*)d_in[4];
    const float* b1     = (const float*)d_in[5];
    const float* w2     = (const float*)d_in[6];
    const float* w_ih   = (const float*)d_in[7];
    const float* w_hh   = (const float*)d_in[8];
    const float* b_ih   = (const float*)d_in[9];
    const float* b_hh   = (const float*)d_in[10];
    const float* out0_w = (const float*)d_in[11];
    const float* out0_b = (const float*)d_in[12];
    const float* out1_w = (const float*)d_in[13];
    const float* out1_b = (const float*)d_in[14];
    float* out = (float*)d_out;

    char* wp = (char*)d_ws;
    auto carve = [&](size_t bytes) { char* p = wp; wp += (bytes + 255) & ~(size_t)255; return p; };
    __hip_bfloat16* enc_bf  = (__hip_bfloat16*)carve((size_t)B_SZ * S_SZ * H_SZ * 2);
    __hip_bfloat16* encp_bf = (__hip_bfloat16*)carve((size_t)B_SZ * S_SZ * H_SZ * 2);
    __hip_bfloat16* w1a_bf  = (__hip_bfloat16*)carve((size_t)H_SZ * H_SZ * 2);        // w1[:, :H]
    __hip_bfloat16* wcat_bf = (__hip_bfloat16*)carve((size_t)NG * H_SZ * 2);          // [w1[:,H:] ; w_hh]
    __hip_bfloat16* wih_bf  = (__hip_bfloat16*)carve((size_t)3 * H_SZ * XW * 2);
    __hip_bfloat16* o0_bf   = (__hip_bfloat16*)carve((size_t)V_SZ * H_SZ * 2);
    __hip_bfloat16* o1_bf   = (__hip_bfloat16*)carve((size_t)V_SZ * H_SZ * 2);
    float*          bias_cat= (float*)carve((size_t)NG * 4);
    float*          h       = (float*)carve((size_t)B_SZ * H_SZ * 4);
    __hip_bfloat16* h_bf    = (__hip_bfloat16*)carve((size_t)B_SZ * H_SZ * 2);
    __hip_bfloat16* hg_bf   = (__hip_bfloat16*)carve((size_t)B_SZ * NG * 2);          // [hproj|gh]
    __hip_bfloat16* x_bf[3];
    for (int t = 0; t < 3; ++t) x_bf[t] = (__hip_bfloat16*)carve((size_t)B_SZ * XW * 2);
    __hip_bfloat16* gi_bf   = (__hip_bfloat16*)carve((size_t)B_SZ * 3 * H_SZ * 2);

    // --- one-time prep ---
    cast_f32_to_bf16<<<2048, 256, 0, stream>>>(enc, H_SZ, H_SZ, enc_bf, B_SZ * S_SZ);
    {
        CastSeg s0{w1,            2 * H_SZ, H_SZ / 4, w1a_bf,                        (long long)H_SZ * H_SZ / 4};
        CastSeg s1{w1 + H_SZ,     2 * H_SZ, H_SZ / 4, wcat_bf,                       (long long)H_SZ * H_SZ / 4};
        CastSeg s2{w_hh,          H_SZ,     H_SZ / 4, wcat_bf + (size_t)H_SZ * H_SZ, (long long)3 * H_SZ * H_SZ / 4};
        CastSeg s3{w_ih,          XW,       XW / 4,   wih_bf,                        (long long)3 * H_SZ * XW / 4};
        CastSeg s4{out0_w,        H_SZ,     H_SZ / 4, o0_bf,                         (long long)V_SZ * H_SZ / 4};
        CastSeg s5{out1_w,        H_SZ,     H_SZ / 4, o1_bf,                         (long long)V_SZ * H_SZ / 4};
        cast_all_kernel<<<2048, 256, 0, stream>>>(s0, s1, s2, s3, s4, s5);
    }
    build_bias_cat<<<NG / 256, 256, 0, stream>>>(b1, b_hh, bias_cat);
    emb_prefill_kernel<<<3 * B_SZ, 128, 0, stream>>>(emb, tgt, x_bf[0], x_bf[1], x_bf[2]);
    h_init_kernel<<<(B_SZ * H_SZ / 4) / 256, 256, 0, stream>>>(enc_h, h, h_bf);

    // enc_proj = enc @ w1[:, :H].T  (timestep-invariant, bf16 out, XCD-swizzled: A-heavy)
    gemm_bt_mfma<1, 1><<<(B_SZ * S_SZ / 128) * (H_SZ / 128), 256, 0, stream>>>(
        enc_bf, H_SZ, w1a_bf, H_SZ, nullptr, encp_bf, H_SZ, H_SZ / 128, H_SZ, H_SZ);

    // hg(0) = h0 @ [w1_h | w_hh].T + [b1 | b_hh]
    gemm_bt_mfma<1, 0><<<(B_SZ / 128) * (NG / 128), 256, 0, stream>>>(
        h_bf, H_SZ, wcat_bf, H_SZ, bias_cat, hg_bf, NG, NG / 128, NG, H_SZ);

    for (int t = 0; t < 3; ++t) {
        attn_ctx_kernel<<<B_SZ, 256, 0, stream>>>(enc_bf, encp_bf, hg_bf, w2, x_bf[t]);

        // gi = x @ w_ih.T + b_ih  (bf16 out)
        gemm_bt_mfma<1, 0><<<(B_SZ / 128) * (3 * H_SZ / 128), 256, 0, stream>>>(
            x_bf[t], XW, wih_bf, XW, b_ih, gi_bf, 3 * H_SZ, 3 * H_SZ / 128, 3 * H_SZ, XW);

        gru_gate_kernel<<<(B_SZ * H_SZ) / 256, 256, 0, stream>>>(gi_bf, hg_bf, h, h_bf);

        // [hg(t+1) | logits(t)] = h @ [wcat | ow].T   (dual output; hg skipped at t==2)
        float* logits = out + (size_t)t * B_SZ * V_SZ;
        const __hip_bfloat16* ow = (t == 1) ? o1_bf : o0_bf;
        const float* ob = (t == 1) ? out1_b : out0_b;
        gemm_dual_mfma<<<(B_SZ / 128) * 64, 256, 0, stream>>>(
            h_bf, wcat_bf, ow, bias_cat, ob, hg_bf, logits, (t < 2) ? 1 : 0);

        logsoftmax_kernel<<<B_SZ, 256, 0, stream>>>(logits);
    }
}

// Round 5
// 568.231 us; speedup vs baseline: 6.9576x; 1.0486x over previous
//
#include <hip/hip_runtime.h>
#include <hip/hip_bf16.h>
#include <math.h>

#define B_SZ 1024
#define S_SZ 40
#define H_SZ 1024
#define DW_SZ 512
#define V_SZ 4000
#define XW (DW_SZ + H_SZ)      // 1536
#define NG (4 * H_SZ)          // 4096: [hproj | gh(3H)]

typedef __bf16 bf16x8 __attribute__((ext_vector_type(8)));
typedef float f32x4 __attribute__((ext_vector_type(4)));

__device__ __forceinline__ float fast_tanh(float x) {
    return 1.0f - 2.0f / (1.0f + __expf(2.0f * x));
}
__device__ __forceinline__ float fast_sigmoid(float x) {
    return 1.0f / (1.0f + __expf(-x));
}
__device__ __forceinline__ float bfraw2f(unsigned short u) {
    return __uint_as_float(((unsigned)u) << 16);
}

#define GLL16(gp, lp)                                                                \
    __builtin_amdgcn_global_load_lds((const __attribute__((address_space(1))) void*)(gp), \
                                     (__attribute__((address_space(3))) void*)(lp), 16, 0, 0)

// ================= 256x256 tile, BK=32, 3-slot counted-vmcnt pipelined GEMM =================
// C[m,n] = sum_k A[m,k]*W[n,k]  (bf16 out, no bias). M%256==0, N%256==0, K%32==0, K/32>=3.
// 512 threads = 8 waves (2m x 4n), wave tile 128x64 (8x4 frags of 16x16x32).
// LDS: 3 slots x 32KB (A 16KB + B 16KB), dynamic. Prefetch depth 2; vmcnt(4) per tile (never 0).
// T2 swizzle: 16B-slot index ^= (row>>1)&3, applied to BOTH global source and ds_read (involution).
__global__ __launch_bounds__(512, 2) void gemm_bt_256_pipe(
    const __hip_bfloat16* __restrict__ A, int lda,
    const __hip_bfloat16* __restrict__ W, int ldw,
    __hip_bfloat16* __restrict__ C, int ldc,
    int nbx, int K) {
    extern __shared__ char smem[];   // 3 * 32768 bytes
    const int tid = threadIdx.x;
    const int lane = tid & 63;
    const int wave = tid >> 6;
    const int wm = wave >> 2, wn = wave & 3;
    const int fr = lane & 15, fq = lane >> 4;

    int bid = blockIdx.x;
    { const int cpx = gridDim.x >> 3; bid = (bid & 7) * cpx + (bid >> 3); }  // XCD swizzle (grid%8==0)
    const int by = bid / nbx;
    const int bm = by * 256;
    const int bn = (bid - by * nbx) * 256;

    // staging: chunk c in {tid, tid+512}; row=c>>2, phys 16B-slot p=c&3, logical slot s=p^((row>>1)&3)
    const int r0 = tid >> 2;                       // 0..127 (second chunk: +128)
    const int s0 = (tid & 3) ^ ((tid >> 3) & 3);   // same for both chunks (128%4==0 in (row>>1)&3... 64&3==0)
    const __hip_bfloat16* gA0 = A + (size_t)(bm + r0) * lda + s0 * 8;
    const __hip_bfloat16* gA1 = A + (size_t)(bm + r0 + 128) * lda + s0 * 8;
    const __hip_bfloat16* gW0 = W + (size_t)(bn + r0) * ldw + s0 * 8;
    const __hip_bfloat16* gW1 = W + (size_t)(bn + r0 + 128) * ldw + s0 * 8;
    const int dst0 = tid * 16;                     // byte offset within A region of slot

    // ds_read offsets (byte, within slot): A at +0, B at +16384
    int aoff[8], boff[4];
#pragma unroll
    for (int mi = 0; mi < 8; ++mi) {
        const int row = wm * 128 + mi * 16 + fr;
        aoff[mi] = row * 64 + ((fq ^ ((row >> 1) & 3)) << 4);
    }
#pragma unroll
    for (int ni = 0; ni < 4; ++ni) {
        const int col = wn * 64 + ni * 16 + fr;
        boff[ni] = 16384 + col * 64 + ((fq ^ ((col >> 1) & 3)) << 4);
    }

    const int NT = K >> 5;
    f32x4 acc[8][4] = {};

#define STAGE_T(t)                                                    \
    do {                                                              \
        char* sb = smem + ((t) % 3) * 32768;                          \
        const int kk = (t) << 5;                                      \
        GLL16(gA0 + kk, sb + dst0);                                   \
        GLL16(gA1 + kk, sb + dst0 + 8192);                            \
        GLL16(gW0 + kk, sb + 16384 + dst0);                           \
        GLL16(gW1 + kk, sb + 16384 + dst0 + 8192);                    \
    } while (0)

    STAGE_T(0);
    STAGE_T(1);
    __builtin_amdgcn_sched_barrier(0);
    asm volatile("s_waitcnt vmcnt(4)" ::: "memory");   // tile 0 landed (tile 1 in flight)
    __builtin_amdgcn_s_barrier();
    __builtin_amdgcn_sched_barrier(0);

    for (int t = 0; t < NT; ++t) {
        if (t + 2 < NT) STAGE_T(t + 2);

        const char* sb = smem + (t % 3) * 32768;
        bf16x8 af[8], bg[4];
#pragma unroll
        for (int ni = 0; ni < 4; ++ni) bg[ni] = *reinterpret_cast<const bf16x8*>(sb + boff[ni]);
#pragma unroll
        for (int mi = 0; mi < 8; ++mi) af[mi] = *reinterpret_cast<const bf16x8*>(sb + aoff[mi]);

        __builtin_amdgcn_s_setprio(1);
#pragma unroll
        for (int mi = 0; mi < 8; ++mi)
#pragma unroll
            for (int ni = 0; ni < 4; ++ni)
                acc[mi][ni] = __builtin_amdgcn_mfma_f32_16x16x32_bf16(af[mi], bg[ni], acc[mi][ni], 0, 0, 0);
        __builtin_amdgcn_s_setprio(0);

        if (t != NT - 1) {
            __builtin_amdgcn_sched_barrier(0);
            if (t + 2 < NT) asm volatile("s_waitcnt vmcnt(4)" ::: "memory");  // tile t+1 ready
            else            asm volatile("s_waitcnt vmcnt(0)" ::: "memory");
            __builtin_amdgcn_s_barrier();
            __builtin_amdgcn_sched_barrier(0);
        }
    }
#undef STAGE_T

    // epilogue: C/D layout col=lane&15, row=(lane>>4)*4+reg
#pragma unroll
    for (int mi = 0; mi < 8; ++mi) {
        const int row0 = bm + wm * 128 + mi * 16 + fq * 4;
#pragma unroll
        for (int ni = 0; ni < 4; ++ni) {
            const int col = bn + wn * 64 + ni * 16 + fr;
#pragma unroll
            for (int r = 0; r < 4; ++r)
                C[(size_t)(row0 + r) * ldc + col] = __float2bfloat16(acc[mi][ni][r]);
        }
    }
}

// ---------------- bf16 MFMA GEMM (128x128, 2-barrier): C = A@W.T + bias ----------------
template <int OB, int SWZ>  // OB 1: bf16 out, 0: fp32 out
__global__ __launch_bounds__(256) void gemm_bt_mfma(
    const __hip_bfloat16* __restrict__ A, int lda,
    const __hip_bfloat16* __restrict__ W, int ldw,
    const float* __restrict__ bias,
    void* __restrict__ Cv, int ldc,
    int nbx, int N, int K) {
    __shared__ __align__(16) __hip_bfloat16 As[128 * 32];
    __shared__ __align__(16) __hip_bfloat16 Ws[128 * 32];
    const int tid = threadIdx.x;
    const int lane = tid & 63;
    const int wave = tid >> 6;

    int bid = blockIdx.x;
    if (SWZ) {
        const int cpx = gridDim.x >> 3;
        bid = (bid & 7) * cpx + (bid >> 3);
    }
    const int by = bid / nbx;
    const int bx = bid - by * nbx;
    const int bm = by * 128;
    const int bn = bx * 128;

    const int r0 = tid >> 2;
    const int kk = (tid & 3) * 8;
    const __hip_bfloat16* gA0 = A + (size_t)(bm + r0) * lda + kk;
    const __hip_bfloat16* gA1 = gA0 + (size_t)64 * lda;
    int wrow0 = bn + r0;      if (wrow0 > N - 1) wrow0 = N - 1;
    int wrow1 = bn + r0 + 64; if (wrow1 > N - 1) wrow1 = N - 1;
    const __hip_bfloat16* gW0 = W + (size_t)wrow0 * ldw + kk;
    const __hip_bfloat16* gW1 = W + (size_t)wrow1 * ldw + kk;
    char* As_c = (char*)As + tid * 16;
    char* Ws_c = (char*)Ws + tid * 16;

    const int wr = wave >> 1, wc = wave & 1;
    const int fr = lane & 15, fq = lane >> 4;
    const __hip_bfloat16* Ard = &As[(wr * 64 + fr) * 32 + fq * 8];
    const __hip_bfloat16* Wrd = &Ws[(wc * 64 + fr) * 32 + fq * 8];

    f32x4 acc[4][4] = {};

    for (int k0 = 0; k0 < K; k0 += 32) {
        __syncthreads();
        GLL16(gA0 + k0, As_c);
        GLL16(gA1 + k0, As_c + 4096);
        GLL16(gW0 + k0, Ws_c);
        GLL16(gW1 + k0, Ws_c + 4096);
        __syncthreads();

        bf16x8 af[4], bg[4];
#pragma unroll
        for (int i = 0; i < 4; ++i) {
            af[i] = *reinterpret_cast<const bf16x8*>(Ard + i * 16 * 32);
            bg[i] = *reinterpret_cast<const bf16x8*>(Wrd + i * 16 * 32);
        }
#pragma unroll
        for (int mi = 0; mi < 4; ++mi)
#pragma unroll
            for (int ni = 0; ni < 4; ++ni)
                acc[mi][ni] = __builtin_amdgcn_mfma_f32_16x16x32_bf16(af[mi], bg[ni], acc[mi][ni], 0, 0, 0);
    }

    // C/D layout: col = lane&15, row = (lane>>4)*4 + reg
#pragma unroll
    for (int ni = 0; ni < 4; ++ni) {
        const int col = bn + wc * 64 + ni * 16 + fr;
        if (col >= N) continue;
        const float bb = bias ? bias[col] : 0.0f;
#pragma unroll
        for (int mi = 0; mi < 4; ++mi) {
            const int row0 = bm + wr * 64 + mi * 16 + fq * 4;
#pragma unroll
            for (int r = 0; r < 4; ++r) {
                const float v = acc[mi][ni][r] + bb;
                if (OB)
                    reinterpret_cast<__hip_bfloat16*>(Cv)[(size_t)(row0 + r) * ldc + col] = __float2bfloat16(v);
                else
                    reinterpret_cast<float*>(Cv)[(size_t)(row0 + r) * ldc + col] = v;
            }
        }
    }
}

// ---------------- dual GEMM: cols [0,4096) -> hg (bf16); cols [4096,..) -> logits (fp32) ----------------
__global__ __launch_bounds__(256) void gemm_dual_mfma(
    const __hip_bfloat16* __restrict__ A,
    const __hip_bfloat16* __restrict__ Wg,   // wcat [4096][1024]
    const __hip_bfloat16* __restrict__ Wo,   // out*_w [4000][1024]
    const float* __restrict__ bias_cat,
    const float* __restrict__ ob,
    __hip_bfloat16* __restrict__ hg,
    float* __restrict__ logits,
    int full) {
    const int nbx = 64;
    const int bid = blockIdx.x;
    const int by = bid / nbx;
    const int bx = bid - by * nbx;
    const int bm = by * 128;
    const int bn = bx * 128;
    const int is_hg = (bn < NG);
    if (!full && is_hg) return;

    __shared__ __align__(16) __hip_bfloat16 As[128 * 32];
    __shared__ __align__(16) __hip_bfloat16 Ws[128 * 32];
    const int tid = threadIdx.x;
    const int lane = tid & 63;
    const int wave = tid >> 6;

    const __hip_bfloat16* Wb = is_hg ? Wg : Wo;
    const int coff = is_hg ? bn : bn - NG;
    const int nn = is_hg ? NG : V_SZ;

    const int r0 = tid >> 2;
    const int kk = (tid & 3) * 8;
    const __hip_bfloat16* gA0 = A + (size_t)(bm + r0) * H_SZ + kk;
    const __hip_bfloat16* gA1 = gA0 + (size_t)64 * H_SZ;
    int wrow0 = coff + r0;      if (wrow0 > nn - 1) wrow0 = nn - 1;
    int wrow1 = coff + r0 + 64; if (wrow1 > nn - 1) wrow1 = nn - 1;
    const __hip_bfloat16* gW0 = Wb + (size_t)wrow0 * H_SZ + kk;
    const __hip_bfloat16* gW1 = Wb + (size_t)wrow1 * H_SZ + kk;
    char* As_c = (char*)As + tid * 16;
    char* Ws_c = (char*)Ws + tid * 16;

    const int wr = wave >> 1, wc = wave & 1;
    const int fr = lane & 15, fq = lane >> 4;
    const __hip_bfloat16* Ard = &As[(wr * 64 + fr) * 32 + fq * 8];
    const __hip_bfloat16* Wrd = &Ws[(wc * 64 + fr) * 32 + fq * 8];

    f32x4 acc[4][4] = {};

    for (int k0 = 0; k0 < H_SZ; k0 += 32) {
        __syncthreads();
        GLL16(gA0 + k0, As_c);
        GLL16(gA1 + k0, As_c + 4096);
        GLL16(gW0 + k0, Ws_c);
        GLL16(gW1 + k0, Ws_c + 4096);
        __syncthreads();

        bf16x8 af[4], bg[4];
#pragma unroll
        for (int i = 0; i < 4; ++i) {
            af[i] = *reinterpret_cast<const bf16x8*>(Ard + i * 16 * 32);
            bg[i] = *reinterpret_cast<const bf16x8*>(Wrd + i * 16 * 32);
        }
#pragma unroll
        for (int mi = 0; mi < 4; ++mi)
#pragma unroll
            for (int ni = 0; ni < 4; ++ni)
                acc[mi][ni] = __builtin_amdgcn_mfma_f32_16x16x32_bf16(af[mi], bg[ni], acc[mi][ni], 0, 0, 0);
    }

#pragma unroll
    for (int ni = 0; ni < 4; ++ni) {
        const int cl = coff + wc * 64 + ni * 16 + fr;
        if (cl >= nn) continue;
        const float bb = is_hg ? bias_cat[cl] : ob[cl];
#pragma unroll
        for (int mi = 0; mi < 4; ++mi) {
            const int row0 = bm + wr * 64 + mi * 16 + fq * 4;
#pragma unroll
            for (int r = 0; r < 4; ++r) {
                const float v = acc[mi][ni][r] + bb;
                if (is_hg)
                    hg[(size_t)(row0 + r) * NG + cl] = __float2bfloat16(v);
                else
                    logits[(size_t)(row0 + r) * V_SZ + cl] = v;
            }
        }
    }
}

// ---------------- fp32 -> bf16 cast (strided rows) ----------------
__global__ __launch_bounds__(256) void cast_f32_to_bf16(
    const float* __restrict__ src, long long sstride, int cols,
    __hip_bfloat16* __restrict__ dst, int nrows) {
    const int c4n = cols >> 2;
    const long long total4 = (long long)nrows * c4n;
    for (long long i = (long long)blockIdx.x * 256 + threadIdx.x; i < total4;
         i += (long long)gridDim.x * 256) {
        const long long r = i / c4n;
        const int c = (int)(i - r * c4n) << 2;
        const float4 v = *reinterpret_cast<const float4*>(src + r * sstride + c);
        union { ushort4 u; __hip_bfloat16 h[4]; } o;
        o.h[0] = __float2bfloat16(v.x); o.h[1] = __float2bfloat16(v.y);
        o.h[2] = __float2bfloat16(v.z); o.h[3] = __float2bfloat16(v.w);
        *reinterpret_cast<ushort4*>(dst + r * (long long)cols + c) = o.u;
    }
}

// ---------------- unified weight cast ----------------
struct CastSeg { const float* src; long long sstride; int c4n; __hip_bfloat16* dst; long long n4; };
__global__ __launch_bounds__(256) void cast_all_kernel(CastSeg s0, CastSeg s1, CastSeg s2,
                                                       CastSeg s3, CastSeg s4, CastSeg s5) {
    const long long e0 = s0.n4, e1 = e0 + s1.n4, e2 = e1 + s2.n4,
                    e3 = e2 + s3.n4, e4 = e3 + s4.n4, e5 = e4 + s5.n4;
    for (long long i = (long long)blockIdx.x * 256 + threadIdx.x; i < e5;
         i += (long long)gridDim.x * 256) {
        CastSeg sg; long long li = i;
        if (i < e0) { sg = s0; }
        else if (i < e1) { sg = s1; li -= e0; }
        else if (i < e2) { sg = s2; li -= e1; }
        else if (i < e3) { sg = s3; li -= e2; }
        else if (i < e4) { sg = s4; li -= e3; }
        else { sg = s5; li -= e4; }
        const long long r = li / sg.c4n;
        const int c = (int)(li - r * sg.c4n) << 2;
        const float4 v = *reinterpret_cast<const float4*>(sg.src + r * sg.sstride + c);
        union { ushort4 u; __hip_bfloat16 h[4]; } o;
        o.h[0] = __float2bfloat16(v.x); o.h[1] = __float2bfloat16(v.y);
        o.h[2] = __float2bfloat16(v.z); o.h[3] = __float2bfloat16(v.w);
        *reinterpret_cast<ushort4*>(sg.dst + r * (long long)(sg.c4n << 2) + c) = o.u;
    }
}

// ---------------- bias_cat = [b1 | b_hh] ----------------
__global__ __launch_bounds__(256) void build_bias_cat(
    const float* __restrict__ b1, const float* __restrict__ b_hh,
    float* __restrict__ dst) {
    const int j = blockIdx.x * 256 + threadIdx.x;
    dst[j] = (j < H_SZ) ? b1[j] : b_hh[j - H_SZ];
}

// ---------------- h init ----------------
__global__ __launch_bounds__(256) void h_init_kernel(
    const float* __restrict__ enc_h, float* __restrict__ h, __hip_bfloat16* __restrict__ h_bf) {
    const int i = blockIdx.x * 256 + threadIdx.x;
    const float4 v = reinterpret_cast<const float4*>(enc_h)[i];
    reinterpret_cast<float4*>(h)[i] = v;
    union { ushort4 u; __hip_bfloat16 hh[4]; } o;
    o.hh[0] = __float2bfloat16(v.x); o.hh[1] = __float2bfloat16(v.y);
    o.hh[2] = __float2bfloat16(v.z); o.hh[3] = __float2bfloat16(v.w);
    reinterpret_cast<ushort4*>(h_bf)[i] = o.u;
}

// ---------------- prefill emb halves of x for all 3 steps ----------------
__global__ __launch_bounds__(128) void emb_prefill_kernel(
    const float* __restrict__ emb,
    const int* __restrict__ targets,
    __hip_bfloat16* __restrict__ x0,
    __hip_bfloat16* __restrict__ x1,
    __hip_bfloat16* __restrict__ x2) {
    const int blk = blockIdx.x;
    const int t = blk >> 10;
    const int b = blk & 1023;
    const int tid = threadIdx.x;
    int it;
    __hip_bfloat16* x;
    if (t == 0) { it = 0; x = x0; }
    else if (t == 1) { it = targets[b] + 1; x = x1; }
    else { it = targets[B_SZ + b] + 36; x = x2; }
    float4 v = reinterpret_cast<const float4*>(emb + (size_t)it * DW_SZ)[tid];
    union { ushort4 u; __hip_bfloat16 h[4]; } o;
    o.h[0] = __float2bfloat16(v.x); o.h[1] = __float2bfloat16(v.y);
    o.h[2] = __float2bfloat16(v.z); o.h[3] = __float2bfloat16(v.w);
    reinterpret_cast<ushort4*>(x + (size_t)b * XW)[tid] = o.u;
}

// ---------------- attention (wave-parallel scores) ----------------
__global__ __launch_bounds__(256) void attn_ctx_kernel(
    const __hip_bfloat16* __restrict__ enc,
    const __hip_bfloat16* __restrict__ enc_proj,
    const __hip_bfloat16* __restrict__ hg,     // [B][4096], first H = hproj (incl b1)
    const float* __restrict__ w2,
    __hip_bfloat16* __restrict__ x) {          // [B][XW], write at DW..
    const int b = blockIdx.x;
    const int tid = threadIdx.x;
    const int lane = tid & 63, wave = tid >> 6;
    __shared__ float s_e[S_SZ];

    float hp[16], wv[16];
    const unsigned short* hgrow = reinterpret_cast<const unsigned short*>(hg) + (size_t)b * NG;
#pragma unroll
    for (int p = 0; p < 4; ++p) {
        const int base = p * 256 + lane * 4;
        ushort4 hu = *reinterpret_cast<const ushort4*>(hgrow + base);
        float4 wq = *reinterpret_cast<const float4*>(w2 + base);
        hp[p * 4 + 0] = bfraw2f(hu.x); hp[p * 4 + 1] = bfraw2f(hu.y);
        hp[p * 4 + 2] = bfraw2f(hu.z); hp[p * 4 + 3] = bfraw2f(hu.w);
        wv[p * 4 + 0] = wq.x; wv[p * 4 + 1] = wq.y;
        wv[p * 4 + 2] = wq.z; wv[p * 4 + 3] = wq.w;
    }

    const unsigned short* ep0 = reinterpret_cast<const unsigned short*>(enc_proj) + (size_t)b * S_SZ * H_SZ;
#pragma unroll 2
    for (int i = 0; i < 10; ++i) {
        const int s = wave + 4 * i;
        const unsigned short* row = ep0 + (size_t)s * H_SZ;
        float acc = 0.f;
#pragma unroll
        for (int p = 0; p < 4; ++p) {
            ushort4 eu = *reinterpret_cast<const ushort4*>(row + p * 256 + lane * 4);
            acc += fast_tanh(bfraw2f(eu.x) + hp[p * 4 + 0]) * wv[p * 4 + 0]
                 + fast_tanh(bfraw2f(eu.y) + hp[p * 4 + 1]) * wv[p * 4 + 1]
                 + fast_tanh(bfraw2f(eu.z) + hp[p * 4 + 2]) * wv[p * 4 + 2]
                 + fast_tanh(bfraw2f(eu.w) + hp[p * 4 + 3]) * wv[p * 4 + 3];
        }
#pragma unroll
        for (int off = 32; off > 0; off >>= 1) acc += __shfl_down(acc, off);
        if (lane == 0) s_e[s] = acc;
    }
    __syncthreads();

    float m = -1e30f;
    for (int s = 0; s < S_SZ; ++s) m = fmaxf(m, s_e[s]);
    float sum = 0.f;
    for (int s = 0; s < S_SZ; ++s) sum += __expf(s_e[s] - m);
    const float inv = 1.0f / sum;

    const ushort4* enc_b = reinterpret_cast<const ushort4*>(enc + (size_t)b * S_SZ * H_SZ);
    float4 acc = make_float4(0.f, 0.f, 0.f, 0.f);
    for (int s = 0; s < S_SZ; ++s) {
        const float a = __expf(s_e[s] - m) * inv;
        ushort4 ev = enc_b[s * 256 + tid];
        acc.x += a * bfraw2f(ev.x); acc.y += a * bfraw2f(ev.y);
        acc.z += a * bfraw2f(ev.z); acc.w += a * bfraw2f(ev.w);
    }
    union { ushort4 u; __hip_bfloat16 h[4]; } o;
    o.h[0] = __float2bfloat16(acc.x); o.h[1] = __float2bfloat16(acc.y);
    o.h[2] = __float2bfloat16(acc.z); o.h[3] = __float2bfloat16(acc.w);
    reinterpret_cast<ushort4*>(x + (size_t)b * XW + DW_SZ)[tid] = o.u;
}

// ---------------- GRU gate combine ----------------
__global__ __launch_bounds__(256) void gru_gate_kernel(
    const __hip_bfloat16* __restrict__ gi,   // [B][3H]
    const __hip_bfloat16* __restrict__ hg,   // [B][4H], gh at +H
    float* __restrict__ h,
    __hip_bfloat16* __restrict__ h_bf) {
    const int idx = blockIdx.x * 256 + threadIdx.x;
    const int b = idx >> 10;
    const int j = idx & 1023;
    const unsigned short* gib = reinterpret_cast<const unsigned short*>(gi) + (size_t)b * 3 * H_SZ;
    const unsigned short* ghb = reinterpret_cast<const unsigned short*>(hg) + (size_t)b * NG + H_SZ;
    const float i_r = bfraw2f(gib[j]), i_z = bfraw2f(gib[H_SZ + j]), i_n = bfraw2f(gib[2 * H_SZ + j]);
    const float h_r = bfraw2f(ghb[j]), h_z = bfraw2f(ghb[H_SZ + j]), h_n = bfraw2f(ghb[2 * H_SZ + j]);
    const float r = fast_sigmoid(i_r + h_r);
    const float z = fast_sigmoid(i_z + h_z);
    const float n = fast_tanh(i_n + r * h_n);
    const float hv = (1.0f - z) * n + z * h[idx];
    h[idx] = hv;
    h_bf[idx] = __float2bfloat16(hv);
}

// ---------------- in-place log-softmax over V per row ----------------
__global__ __launch_bounds__(256) void logsoftmax_kernel(float* __restrict__ buf) {
    const int b = blockIdx.x;
    const int tid = threadIdx.x;
    const int lane = tid & 63, wave = tid >> 6;
    __shared__ float s_red[4];
    __shared__ float s_bc;
    float* row = buf + (size_t)b * V_SZ;

    float m = -1e30f;
    for (int k = tid; k < V_SZ; k += 256) m = fmaxf(m, row[k]);
#pragma unroll
    for (int off = 32; off > 0; off >>= 1) m = fmaxf(m, __shfl_down(m, off));
    if (lane == 0) s_red[wave] = m;
    __syncthreads();
    if (tid == 0) s_bc = fmaxf(fmaxf(s_red[0], s_red[1]), fmaxf(s_red[2], s_red[3]));
    __syncthreads();
    m = s_bc;

    float sum = 0.f;
    for (int k = tid; k < V_SZ; k += 256) sum += expf(row[k] - m);
#pragma unroll
    for (int off = 32; off > 0; off >>= 1) sum += __shfl_down(sum, off);
    __syncthreads();
    if (lane == 0) s_red[wave] = sum;
    __syncthreads();
    if (tid == 0) s_bc = logf(s_red[0] + s_red[1] + s_red[2] + s_red[3]) + m;
    __syncthreads();
    const float ls = s_bc;

    for (int k = tid; k < V_SZ; k += 256) row[k] = row[k] - ls;
}

extern "C" void kernel_launch(void* const* d_in, const int* in_sizes, int n_in,
                              void* d_out, int out_size, void* d_ws, size_t ws_size,
                              hipStream_t stream) {
    const float* enc    = (const float*)d_in[0];
    const float* enc_h  = (const float*)d_in[1];
    const int*   tgt    = (const int*)d_in[2];
    const float* emb    = (const float*)d_in[3];
    const float* w1     = (const float*)d_in[4];
    const float* b1     = (const float*)d_in[5];
    const float* w2     = (const float*)d_in[6];
    const float* w_ih   = (const float*)d_in[7];
    const float* w_hh   = (const float*)d_in[8];
    const float* b_ih   = (const float*)d_in[9];
    const float* b_hh   = (const float*)d_in[10];
    const float* out0_w = (const float*)d_in[11];
    const float* out0_b = (const float*)d_in[12];
    const float* out1_w = (const float*)d_in[13];
    const float* out1_b = (const float*)d_in[14];
    float* out = (float*)d_out;

    char* wp = (char*)d_ws;
    auto carve = [&](size_t bytes) { char* p = wp; wp += (bytes + 255) & ~(size_t)255; return p; };
    __hip_bfloat16* enc_bf  = (__hip_bfloat16*)carve((size_t)B_SZ * S_SZ * H_SZ * 2);
    __hip_bfloat16* encp_bf = (__hip_bfloat16*)carve((size_t)B_SZ * S_SZ * H_SZ * 2);
    __hip_bfloat16* w1a_bf  = (__hip_bfloat16*)carve((size_t)H_SZ * H_SZ * 2);        // w1[:, :H]
    __hip_bfloat16* wcat_bf = (__hip_bfloat16*)carve((size_t)NG * H_SZ * 2);          // [w1[:,H:] ; w_hh]
    __hip_bfloat16* wih_bf  = (__hip_bfloat16*)carve((size_t)3 * H_SZ * XW * 2);
    __hip_bfloat16* o0_bf   = (__hip_bfloat16*)carve((size_t)V_SZ * H_SZ * 2);
    __hip_bfloat16* o1_bf   = (__hip_bfloat16*)carve((size_t)V_SZ * H_SZ * 2);
    float*          bias_cat= (float*)carve((size_t)NG * 4);
    float*          h       = (float*)carve((size_t)B_SZ * H_SZ * 4);
    __hip_bfloat16* h_bf    = (__hip_bfloat16*)carve((size_t)B_SZ * H_SZ * 2);
    __hip_bfloat16* hg_bf   = (__hip_bfloat16*)carve((size_t)B_SZ * NG * 2);          // [hproj|gh]
    __hip_bfloat16* x_bf[3];
    for (int t = 0; t < 3; ++t) x_bf[t] = (__hip_bfloat16*)carve((size_t)B_SZ * XW * 2);
    __hip_bfloat16* gi_bf   = (__hip_bfloat16*)carve((size_t)B_SZ * 3 * H_SZ * 2);

    // --- one-time prep ---
    cast_f32_to_bf16<<<2048, 256, 0, stream>>>(enc, H_SZ, H_SZ, enc_bf, B_SZ * S_SZ);
    {
        CastSeg s0{w1,            2 * H_SZ, H_SZ / 4, w1a_bf,                        (long long)H_SZ * H_SZ / 4};
        CastSeg s1{w1 + H_SZ,     2 * H_SZ, H_SZ / 4, wcat_bf,                       (long long)H_SZ * H_SZ / 4};
        CastSeg s2{w_hh,          H_SZ,     H_SZ / 4, wcat_bf + (size_t)H_SZ * H_SZ, (long long)3 * H_SZ * H_SZ / 4};
        CastSeg s3{w_ih,          XW,       XW / 4,   wih_bf,                        (long long)3 * H_SZ * XW / 4};
        CastSeg s4{out0_w,        H_SZ,     H_SZ / 4, o0_bf,                         (long long)V_SZ * H_SZ / 4};
        CastSeg s5{out1_w,        H_SZ,     H_SZ / 4, o1_bf,                         (long long)V_SZ * H_SZ / 4};
        cast_all_kernel<<<2048, 256, 0, stream>>>(s0, s1, s2, s3, s4, s5);
    }
    build_bias_cat<<<NG / 256, 256, 0, stream>>>(b1, b_hh, bias_cat);
    emb_prefill_kernel<<<3 * B_SZ, 128, 0, stream>>>(emb, tgt, x_bf[0], x_bf[1], x_bf[2]);
    h_init_kernel<<<(B_SZ * H_SZ / 4) / 256, 256, 0, stream>>>(enc_h, h, h_bf);

    // enc_proj = enc @ w1[:, :H].T  -- 256x256 counted-vmcnt pipeline, XCD-swizzled (grid 640 % 8 == 0)
    gemm_bt_256_pipe<<<(B_SZ * S_SZ / 256) * (H_SZ / 256), 512, 3 * 32768, stream>>>(
        enc_bf, H_SZ, w1a_bf, H_SZ, encp_bf, H_SZ, H_SZ / 256, H_SZ);

    // hg(0) = h0 @ [w1_h | w_hh].T + [b1 | b_hh]
    gemm_bt_mfma<1, 0><<<(B_SZ / 128) * (NG / 128), 256, 0, stream>>>(
        h_bf, H_SZ, wcat_bf, H_SZ, bias_cat, hg_bf, NG, NG / 128, NG, H_SZ);

    for (int t = 0; t < 3; ++t) {
        attn_ctx_kernel<<<B_SZ, 256, 0, stream>>>(enc_bf, encp_bf, hg_bf, w2, x_bf[t]);

        // gi = x @ w_ih.T + b_ih  (bf16 out)
        gemm_bt_mfma<1, 0><<<(B_SZ / 128) * (3 * H_SZ / 128), 256, 0, stream>>>(
            x_bf[t], XW, wih_bf, XW, b_ih, gi_bf, 3 * H_SZ, 3 * H_SZ / 128, 3 * H_SZ, XW);

        gru_gate_kernel<<<(B_SZ * H_SZ) / 256, 256, 0, stream>>>(gi_bf, hg_bf, h, h_bf);

        // [hg(t+1) | logits(t)] = h @ [wcat | ow].T   (dual output; hg skipped at t==2)
        float* logits = out + (size_t)t * B_SZ * V_SZ;
        const __hip_bfloat16* ow = (t == 1) ? o1_bf : o0_bf;
        const float* ob = (t == 1) ? out1_b : out0_b;
        gemm_dual_mfma<<<(B_SZ / 128) * 64, 256, 0, stream>>>(
            h_bf, wcat_bf, ow, bias_cat, ob, hg_bf, logits, (t < 2) ? 1 : 0);

        logsoftmax_kernel<<<B_SZ, 256, 0, stream>>>(logits);
    }
}

// Round 6
// 556.727 us; speedup vs baseline: 7.1013x; 1.0207x over previous
//
#include <hip/hip_runtime.h>
#include <hip/hip_bf16.h>
#include <math.h>

#define B_SZ 1024
#define S_SZ 40
#define H_SZ 1024
#define DW_SZ 512
#define V_SZ 4000
#define XW (DW_SZ + H_SZ)      // 1536
#define NG (4 * H_SZ)          // 4096: [hproj | gh(3H)]

typedef __bf16 bf16x8 __attribute__((ext_vector_type(8)));
typedef float f32x4 __attribute__((ext_vector_type(4)));

__device__ __forceinline__ float fast_tanh(float x) {
    return 1.0f - 2.0f / (1.0f + __expf(2.0f * x));
}
__device__ __forceinline__ float fast_sigmoid(float x) {
    return 1.0f / (1.0f + __expf(-x));
}
__device__ __forceinline__ float bfraw2f(unsigned short u) {
    return __uint_as_float(((unsigned)u) << 16);
}

#define GLL16(gp, lp)                                                                \
    __builtin_amdgcn_global_load_lds((const __attribute__((address_space(1))) void*)(gp), \
                                     (__attribute__((address_space(3))) void*)(lp), 16, 0, 0)

// ========== 128x256 tile, BK=32, 3-slot counted-vmcnt pipelined GEMM, 2 blocks/CU ==========
// C[m,n] = sum_k A[m,k]*W[n,k] (bf16 out). M%128==0, N%256==0, K%32==0, K/32>=3, grid%8==0.
// 256 threads = 4 waves (2m x 2n), wave tile 64x128 (4x8 frags of 16x16x32).
// LDS: 3 slots x 24KB (A 8KB + B 16KB) = 72KB -> 2 blocks/CU for cross-block overlap.
// Swizzle: 16B-slot ^= (row>>1)&3 on BOTH global source and ds_read (involution; 0 conflicts r5).
__global__ __launch_bounds__(256, 2) void gemm_bt_pipe128(
    const __hip_bfloat16* __restrict__ A, int lda,
    const __hip_bfloat16* __restrict__ W, int ldw,
    __hip_bfloat16* __restrict__ C, int ldc,
    int nbx, int K) {
    extern __shared__ char smem[];   // 3 * 24576 bytes
    const int tid = threadIdx.x;
    const int lane = tid & 63;
    const int wave = tid >> 6;           // 0..3
    const int wm = wave >> 1, wn = wave & 1;
    const int fr = lane & 15, fq = lane >> 4;

    int bid = blockIdx.x;
    { const int cpx = gridDim.x >> 3; bid = (bid & 7) * cpx + (bid >> 3); }  // XCD swizzle
    const int by = bid / nbx;
    const int bm = by * 128;
    const int bn = (bid - by * nbx) * 256;

    // staging: chunk c -> row c>>2, phys 16B-slot c&3, logical slot (c&3)^((row>>1)&3)
    // rows jump by 64 per 256-chunk stride -> (row>>1)&3 invariant across j  (64/2 % 4 == 0)
    const int r0 = tid >> 2;
    const int s0 = (tid & 3) ^ ((tid >> 3) & 3);
    const __hip_bfloat16* gA0 = A + (size_t)(bm + r0) * lda + s0 * 8;
    const __hip_bfloat16* gA1 = A + (size_t)(bm + r0 + 64) * lda + s0 * 8;
    const __hip_bfloat16* gW0 = W + (size_t)(bn + r0) * ldw + s0 * 8;
    const __hip_bfloat16* gW1 = W + (size_t)(bn + r0 + 64) * ldw + s0 * 8;
    const __hip_bfloat16* gW2 = W + (size_t)(bn + r0 + 128) * ldw + s0 * 8;
    const __hip_bfloat16* gW3 = W + (size_t)(bn + r0 + 192) * ldw + s0 * 8;
    const int dst0 = tid * 16;

    // ds_read byte offsets within slot: A at +0 (8KB), B at +8192 (16KB)
    int aoff[4], boff[8];
#pragma unroll
    for (int mi = 0; mi < 4; ++mi) {
        const int row = wm * 64 + mi * 16 + fr;
        aoff[mi] = row * 64 + ((fq ^ ((row >> 1) & 3)) << 4);
    }
#pragma unroll
    for (int ni = 0; ni < 8; ++ni) {
        const int col = wn * 128 + ni * 16 + fr;
        boff[ni] = 8192 + col * 64 + ((fq ^ ((col >> 1) & 3)) << 4);
    }

    const int NT = K >> 5;
    f32x4 acc[4][8] = {};

#define STAGE_T(t)                                                    \
    do {                                                              \
        char* sb = smem + ((t) % 3) * 24576;                          \
        const int kk = (t) << 5;                                      \
        GLL16(gA0 + kk, sb + dst0);                                   \
        GLL16(gA1 + kk, sb + dst0 + 4096);                            \
        GLL16(gW0 + kk, sb + 8192 + dst0);                            \
        GLL16(gW1 + kk, sb + 8192 + dst0 + 4096);                     \
        GLL16(gW2 + kk, sb + 8192 + dst0 + 8192);                     \
        GLL16(gW3 + kk, sb + 8192 + dst0 + 12288);                    \
    } while (0)

    STAGE_T(0);
    STAGE_T(1);
    __builtin_amdgcn_sched_barrier(0);
    asm volatile("s_waitcnt vmcnt(6)" ::: "memory");   // tile 0 landed (tile 1 in flight)
    __builtin_amdgcn_s_barrier();
    __builtin_amdgcn_sched_barrier(0);

    for (int t = 0; t < NT; ++t) {
        if (t + 2 < NT) STAGE_T(t + 2);

        const char* sb = smem + (t % 3) * 24576;
        bf16x8 af[4], bg[8];
#pragma unroll
        for (int ni = 0; ni < 8; ++ni) bg[ni] = *reinterpret_cast<const bf16x8*>(sb + boff[ni]);
#pragma unroll
        for (int mi = 0; mi < 4; ++mi) af[mi] = *reinterpret_cast<const bf16x8*>(sb + aoff[mi]);

        __builtin_amdgcn_s_setprio(1);
#pragma unroll
        for (int mi = 0; mi < 4; ++mi)
#pragma unroll
            for (int ni = 0; ni < 8; ++ni)
                acc[mi][ni] = __builtin_amdgcn_mfma_f32_16x16x32_bf16(af[mi], bg[ni], acc[mi][ni], 0, 0, 0);
        __builtin_amdgcn_s_setprio(0);

        if (t != NT - 1) {
            __builtin_amdgcn_sched_barrier(0);
            if (t + 2 < NT) asm volatile("s_waitcnt vmcnt(6)" ::: "memory");  // tile t+1 ready
            else            asm volatile("s_waitcnt vmcnt(0)" ::: "memory");
            __builtin_amdgcn_s_barrier();
            __builtin_amdgcn_sched_barrier(0);
        }
    }
#undef STAGE_T

    // epilogue: C/D layout col=lane&15, row=(lane>>4)*4+reg
#pragma unroll
    for (int mi = 0; mi < 4; ++mi) {
        const int row0 = bm + wm * 64 + mi * 16 + fq * 4;
#pragma unroll
        for (int ni = 0; ni < 8; ++ni) {
            const int col = bn + wn * 128 + ni * 16 + fr;
#pragma unroll
            for (int r = 0; r < 4; ++r)
                C[(size_t)(row0 + r) * ldc + col] = __float2bfloat16(acc[mi][ni][r]);
        }
    }
}

// ---------------- bf16 MFMA GEMM (128x128, 2-barrier): C = A@W.T + bias ----------------
template <int OB, int SWZ>  // OB 1: bf16 out, 0: fp32 out
__global__ __launch_bounds__(256) void gemm_bt_mfma(
    const __hip_bfloat16* __restrict__ A, int lda,
    const __hip_bfloat16* __restrict__ W, int ldw,
    const float* __restrict__ bias,
    void* __restrict__ Cv, int ldc,
    int nbx, int N, int K) {
    __shared__ __align__(16) __hip_bfloat16 As[128 * 32];
    __shared__ __align__(16) __hip_bfloat16 Ws[128 * 32];
    const int tid = threadIdx.x;
    const int lane = tid & 63;
    const int wave = tid >> 6;

    int bid = blockIdx.x;
    if (SWZ) {
        const int cpx = gridDim.x >> 3;
        bid = (bid & 7) * cpx + (bid >> 3);
    }
    const int by = bid / nbx;
    const int bx = bid - by * nbx;
    const int bm = by * 128;
    const int bn = bx * 128;

    const int r0 = tid >> 2;
    const int kk = (tid & 3) * 8;
    const __hip_bfloat16* gA0 = A + (size_t)(bm + r0) * lda + kk;
    const __hip_bfloat16* gA1 = gA0 + (size_t)64 * lda;
    int wrow0 = bn + r0;      if (wrow0 > N - 1) wrow0 = N - 1;
    int wrow1 = bn + r0 + 64; if (wrow1 > N - 1) wrow1 = N - 1;
    const __hip_bfloat16* gW0 = W + (size_t)wrow0 * ldw + kk;
    const __hip_bfloat16* gW1 = W + (size_t)wrow1 * ldw + kk;
    char* As_c = (char*)As + tid * 16;
    char* Ws_c = (char*)Ws + tid * 16;

    const int wr = wave >> 1, wc = wave & 1;
    const int fr = lane & 15, fq = lane >> 4;
    const __hip_bfloat16* Ard = &As[(wr * 64 + fr) * 32 + fq * 8];
    const __hip_bfloat16* Wrd = &Ws[(wc * 64 + fr) * 32 + fq * 8];

    f32x4 acc[4][4] = {};

    for (int k0 = 0; k0 < K; k0 += 32) {
        __syncthreads();
        GLL16(gA0 + k0, As_c);
        GLL16(gA1 + k0, As_c + 4096);
        GLL16(gW0 + k0, Ws_c);
        GLL16(gW1 + k0, Ws_c + 4096);
        __syncthreads();

        bf16x8 af[4], bg[4];
#pragma unroll
        for (int i = 0; i < 4; ++i) {
            af[i] = *reinterpret_cast<const bf16x8*>(Ard + i * 16 * 32);
            bg[i] = *reinterpret_cast<const bf16x8*>(Wrd + i * 16 * 32);
        }
#pragma unroll
        for (int mi = 0; mi < 4; ++mi)
#pragma unroll
            for (int ni = 0; ni < 4; ++ni)
                acc[mi][ni] = __builtin_amdgcn_mfma_f32_16x16x32_bf16(af[mi], bg[ni], acc[mi][ni], 0, 0, 0);
    }

    // C/D layout: col = lane&15, row = (lane>>4)*4 + reg
#pragma unroll
    for (int ni = 0; ni < 4; ++ni) {
        const int col = bn + wc * 64 + ni * 16 + fr;
        if (col >= N) continue;
        const float bb = bias ? bias[col] : 0.0f;
#pragma unroll
        for (int mi = 0; mi < 4; ++mi) {
            const int row0 = bm + wr * 64 + mi * 16 + fq * 4;
#pragma unroll
            for (int r = 0; r < 4; ++r) {
                const float v = acc[mi][ni][r] + bb;
                if (OB)
                    reinterpret_cast<__hip_bfloat16*>(Cv)[(size_t)(row0 + r) * ldc + col] = __float2bfloat16(v);
                else
                    reinterpret_cast<float*>(Cv)[(size_t)(row0 + r) * ldc + col] = v;
            }
        }
    }
}

// ---------------- dual GEMM: cols [0,4096) -> hg (bf16); cols [4096,..) -> logits (fp32) ----------------
__global__ __launch_bounds__(256) void gemm_dual_mfma(
    const __hip_bfloat16* __restrict__ A,
    const __hip_bfloat16* __restrict__ Wg,   // wcat [4096][1024]
    const __hip_bfloat16* __restrict__ Wo,   // out*_w [4000][1024]
    const float* __restrict__ bias_cat,
    const float* __restrict__ ob,
    __hip_bfloat16* __restrict__ hg,
    float* __restrict__ logits,
    int full) {
    const int nbx = 64;
    const int bid = blockIdx.x;
    const int by = bid / nbx;
    const int bx = bid - by * nbx;
    const int bm = by * 128;
    const int bn = bx * 128;
    const int is_hg = (bn < NG);
    if (!full && is_hg) return;

    __shared__ __align__(16) __hip_bfloat16 As[128 * 32];
    __shared__ __align__(16) __hip_bfloat16 Ws[128 * 32];
    const int tid = threadIdx.x;
    const int lane = tid & 63;
    const int wave = tid >> 6;

    const __hip_bfloat16* Wb = is_hg ? Wg : Wo;
    const int coff = is_hg ? bn : bn - NG;
    const int nn = is_hg ? NG : V_SZ;

    const int r0 = tid >> 2;
    const int kk = (tid & 3) * 8;
    const __hip_bfloat16* gA0 = A + (size_t)(bm + r0) * H_SZ + kk;
    const __hip_bfloat16* gA1 = gA0 + (size_t)64 * H_SZ;
    int wrow0 = coff + r0;      if (wrow0 > nn - 1) wrow0 = nn - 1;
    int wrow1 = coff + r0 + 64; if (wrow1 > nn - 1) wrow1 = nn - 1;
    const __hip_bfloat16* gW0 = Wb + (size_t)wrow0 * H_SZ + kk;
    const __hip_bfloat16* gW1 = Wb + (size_t)wrow1 * H_SZ + kk;
    char* As_c = (char*)As + tid * 16;
    char* Ws_c = (char*)Ws + tid * 16;

    const int wr = wave >> 1, wc = wave & 1;
    const int fr = lane & 15, fq = lane >> 4;
    const __hip_bfloat16* Ard = &As[(wr * 64 + fr) * 32 + fq * 8];
    const __hip_bfloat16* Wrd = &Ws[(wc * 64 + fr) * 32 + fq * 8];

    f32x4 acc[4][4] = {};

    for (int k0 = 0; k0 < H_SZ; k0 += 32) {
        __syncthreads();
        GLL16(gA0 + k0, As_c);
        GLL16(gA1 + k0, As_c + 4096);
        GLL16(gW0 + k0, Ws_c);
        GLL16(gW1 + k0, Ws_c + 4096);
        __syncthreads();

        bf16x8 af[4], bg[4];
#pragma unroll
        for (int i = 0; i < 4; ++i) {
            af[i] = *reinterpret_cast<const bf16x8*>(Ard + i * 16 * 32);
            bg[i] = *reinterpret_cast<const bf16x8*>(Wrd + i * 16 * 32);
        }
#pragma unroll
        for (int mi = 0; mi < 4; ++mi)
#pragma unroll
            for (int ni = 0; ni < 4; ++ni)
                acc[mi][ni] = __builtin_amdgcn_mfma_f32_16x16x32_bf16(af[mi], bg[ni], acc[mi][ni], 0, 0, 0);
    }

#pragma unroll
    for (int ni = 0; ni < 4; ++ni) {
        const int cl = coff + wc * 64 + ni * 16 + fr;
        if (cl >= nn) continue;
        const float bb = is_hg ? bias_cat[cl] : ob[cl];
#pragma unroll
        for (int mi = 0; mi < 4; ++mi) {
            const int row0 = bm + wr * 64 + mi * 16 + fq * 4;
#pragma unroll
            for (int r = 0; r < 4; ++r) {
                const float v = acc[mi][ni][r] + bb;
                if (is_hg)
                    hg[(size_t)(row0 + r) * NG + cl] = __float2bfloat16(v);
                else
                    logits[(size_t)(row0 + r) * V_SZ + cl] = v;
            }
        }
    }
}

// ---------------- fp32 -> bf16 cast (strided rows) ----------------
__global__ __launch_bounds__(256) void cast_f32_to_bf16(
    const float* __restrict__ src, long long sstride, int cols,
    __hip_bfloat16* __restrict__ dst, int nrows) {
    const int c4n = cols >> 2;
    const long long total4 = (long long)nrows * c4n;
    for (long long i = (long long)blockIdx.x * 256 + threadIdx.x; i < total4;
         i += (long long)gridDim.x * 256) {
        const long long r = i / c4n;
        const int c = (int)(i - r * c4n) << 2;
        const float4 v = *reinterpret_cast<const float4*>(src + r * sstride + c);
        union { ushort4 u; __hip_bfloat16 h[4]; } o;
        o.h[0] = __float2bfloat16(v.x); o.h[1] = __float2bfloat16(v.y);
        o.h[2] = __float2bfloat16(v.z); o.h[3] = __float2bfloat16(v.w);
        *reinterpret_cast<ushort4*>(dst + r * (long long)cols + c) = o.u;
    }
}

// ---------------- unified weight cast ----------------
struct CastSeg { const float* src; long long sstride; int c4n; __hip_bfloat16* dst; long long n4; };
__global__ __launch_bounds__(256) void cast_all_kernel(CastSeg s0, CastSeg s1, CastSeg s2,
                                                       CastSeg s3, CastSeg s4, CastSeg s5) {
    const long long e0 = s0.n4, e1 = e0 + s1.n4, e2 = e1 + s2.n4,
                    e3 = e2 + s3.n4, e4 = e3 + s4.n4, e5 = e4 + s5.n4;
    for (long long i = (long long)blockIdx.x * 256 + threadIdx.x; i < e5;
         i += (long long)gridDim.x * 256) {
        CastSeg sg; long long li = i;
        if (i < e0) { sg = s0; }
        else if (i < e1) { sg = s1; li -= e0; }
        else if (i < e2) { sg = s2; li -= e1; }
        else if (i < e3) { sg = s3; li -= e2; }
        else if (i < e4) { sg = s4; li -= e3; }
        else { sg = s5; li -= e4; }
        const long long r = li / sg.c4n;
        const int c = (int)(li - r * sg.c4n) << 2;
        const float4 v = *reinterpret_cast<const float4*>(sg.src + r * sg.sstride + c);
        union { ushort4 u; __hip_bfloat16 h[4]; } o;
        o.h[0] = __float2bfloat16(v.x); o.h[1] = __float2bfloat16(v.y);
        o.h[2] = __float2bfloat16(v.z); o.h[3] = __float2bfloat16(v.w);
        *reinterpret_cast<ushort4*>(sg.dst + r * (long long)(sg.c4n << 2) + c) = o.u;
    }
}

// ---------------- bias_cat = [b1 | b_hh] ----------------
__global__ __launch_bounds__(256) void build_bias_cat(
    const float* __restrict__ b1, const float* __restrict__ b_hh,
    float* __restrict__ dst) {
    const int j = blockIdx.x * 256 + threadIdx.x;
    dst[j] = (j < H_SZ) ? b1[j] : b_hh[j - H_SZ];
}

// ---------------- h init ----------------
__global__ __launch_bounds__(256) void h_init_kernel(
    const float* __restrict__ enc_h, float* __restrict__ h, __hip_bfloat16* __restrict__ h_bf) {
    const int i = blockIdx.x * 256 + threadIdx.x;
    const float4 v = reinterpret_cast<const float4*>(enc_h)[i];
    reinterpret_cast<float4*>(h)[i] = v;
    union { ushort4 u; __hip_bfloat16 hh[4]; } o;
    o.hh[0] = __float2bfloat16(v.x); o.hh[1] = __float2bfloat16(v.y);
    o.hh[2] = __float2bfloat16(v.z); o.hh[3] = __float2bfloat16(v.w);
    reinterpret_cast<ushort4*>(h_bf)[i] = o.u;
}

// ---------------- prefill emb halves of x for all 3 steps ----------------
__global__ __launch_bounds__(128) void emb_prefill_kernel(
    const float* __restrict__ emb,
    const int* __restrict__ targets,
    __hip_bfloat16* __restrict__ x0,
    __hip_bfloat16* __restrict__ x1,
    __hip_bfloat16* __restrict__ x2) {
    const int blk = blockIdx.x;
    const int t = blk >> 10;
    const int b = blk & 1023;
    const int tid = threadIdx.x;
    int it;
    __hip_bfloat16* x;
    if (t == 0) { it = 0; x = x0; }
    else if (t == 1) { it = targets[b] + 1; x = x1; }
    else { it = targets[B_SZ + b] + 36; x = x2; }
    float4 v = reinterpret_cast<const float4*>(emb + (size_t)it * DW_SZ)[tid];
    union { ushort4 u; __hip_bfloat16 h[4]; } o;
    o.h[0] = __float2bfloat16(v.x); o.h[1] = __float2bfloat16(v.y);
    o.h[2] = __float2bfloat16(v.z); o.h[3] = __float2bfloat16(v.w);
    reinterpret_cast<ushort4*>(x + (size_t)b * XW)[tid] = o.u;
}

// ---------------- attention (wave-parallel scores) ----------------
__global__ __launch_bounds__(256) void attn_ctx_kernel(
    const __hip_bfloat16* __restrict__ enc,
    const __hip_bfloat16* __restrict__ enc_proj,
    const __hip_bfloat16* __restrict__ hg,     // [B][4096], first H = hproj (incl b1)
    const float* __restrict__ w2,
    __hip_bfloat16* __restrict__ x) {          // [B][XW], write at DW..
    const int b = blockIdx.x;
    const int tid = threadIdx.x;
    const int lane = tid & 63, wave = tid >> 6;
    __shared__ float s_e[S_SZ];

    float hp[16], wv[16];
    const unsigned short* hgrow = reinterpret_cast<const unsigned short*>(hg) + (size_t)b * NG;
#pragma unroll
    for (int p = 0; p < 4; ++p) {
        const int base = p * 256 + lane * 4;
        ushort4 hu = *reinterpret_cast<const ushort4*>(hgrow + base);
        float4 wq = *reinterpret_cast<const float4*>(w2 + base);
        hp[p * 4 + 0] = bfraw2f(hu.x); hp[p * 4 + 1] = bfraw2f(hu.y);
        hp[p * 4 + 2] = bfraw2f(hu.z); hp[p * 4 + 3] = bfraw2f(hu.w);
        wv[p * 4 + 0] = wq.x; wv[p * 4 + 1] = wq.y;
        wv[p * 4 + 2] = wq.z; wv[p * 4 + 3] = wq.w;
    }

    const unsigned short* ep0 = reinterpret_cast<const unsigned short*>(enc_proj) + (size_t)b * S_SZ * H_SZ;
#pragma unroll 2
    for (int i = 0; i < 10; ++i) {
        const int s = wave + 4 * i;
        const unsigned short* row = ep0 + (size_t)s * H_SZ;
        float acc = 0.f;
#pragma unroll
        for (int p = 0; p < 4; ++p) {
            ushort4 eu = *reinterpret_cast<const ushort4*>(row + p * 256 + lane * 4);
            acc += fast_tanh(bfraw2f(eu.x) + hp[p * 4 + 0]) * wv[p * 4 + 0]
                 + fast_tanh(bfraw2f(eu.y) + hp[p * 4 + 1]) * wv[p * 4 + 1]
                 + fast_tanh(bfraw2f(eu.z) + hp[p * 4 + 2]) * wv[p * 4 + 2]
                 + fast_tanh(bfraw2f(eu.w) + hp[p * 4 + 3]) * wv[p * 4 + 3];
        }
#pragma unroll
        for (int off = 32; off > 0; off >>= 1) acc += __shfl_down(acc, off);
        if (lane == 0) s_e[s] = acc;
    }
    __syncthreads();

    float m = -1e30f;
    for (int s = 0; s < S_SZ; ++s) m = fmaxf(m, s_e[s]);
    float sum = 0.f;
    for (int s = 0; s < S_SZ; ++s) sum += __expf(s_e[s] - m);
    const float inv = 1.0f / sum;

    const ushort4* enc_b = reinterpret_cast<const ushort4*>(enc + (size_t)b * S_SZ * H_SZ);
    float4 acc = make_float4(0.f, 0.f, 0.f, 0.f);
    for (int s = 0; s < S_SZ; ++s) {
        const float a = __expf(s_e[s] - m) * inv;
        ushort4 ev = enc_b[s * 256 + tid];
        acc.x += a * bfraw2f(ev.x); acc.y += a * bfraw2f(ev.y);
        acc.z += a * bfraw2f(ev.z); acc.w += a * bfraw2f(ev.w);
    }
    union { ushort4 u; __hip_bfloat16 h[4]; } o;
    o.h[0] = __float2bfloat16(acc.x); o.h[1] = __float2bfloat16(acc.y);
    o.h[2] = __float2bfloat16(acc.z); o.h[3] = __float2bfloat16(acc.w);
    reinterpret_cast<ushort4*>(x + (size_t)b * XW + DW_SZ)[tid] = o.u;
}

// ---------------- GRU gate combine ----------------
__global__ __launch_bounds__(256) void gru_gate_kernel(
    const __hip_bfloat16* __restrict__ gi,   // [B][3H]
    const __hip_bfloat16* __restrict__ hg,   // [B][4H], gh at +H
    float* __restrict__ h,
    __hip_bfloat16* __restrict__ h_bf) {
    const int idx = blockIdx.x * 256 + threadIdx.x;
    const int b = idx >> 10;
    const int j = idx & 1023;
    const unsigned short* gib = reinterpret_cast<const unsigned short*>(gi) + (size_t)b * 3 * H_SZ;
    const unsigned short* ghb = reinterpret_cast<const unsigned short*>(hg) + (size_t)b * NG + H_SZ;
    const float i_r = bfraw2f(gib[j]), i_z = bfraw2f(gib[H_SZ + j]), i_n = bfraw2f(gib[2 * H_SZ + j]);
    const float h_r = bfraw2f(ghb[j]), h_z = bfraw2f(ghb[H_SZ + j]), h_n = bfraw2f(ghb[2 * H_SZ + j]);
    const float r = fast_sigmoid(i_r + h_r);
    const float z = fast_sigmoid(i_z + h_z);
    const float n = fast_tanh(i_n + r * h_n);
    const float hv = (1.0f - z) * n + z * h[idx];
    h[idx] = hv;
    h_bf[idx] = __float2bfloat16(hv);
}

// ---------------- in-place log-softmax over V per row ----------------
__global__ __launch_bounds__(256) void logsoftmax_kernel(float* __restrict__ buf) {
    const int b = blockIdx.x;
    const int tid = threadIdx.x;
    const int lane = tid & 63, wave = tid >> 6;
    __shared__ float s_red[4];
    __shared__ float s_bc;
    float* row = buf + (size_t)b * V_SZ;

    float m = -1e30f;
    for (int k = tid; k < V_SZ; k += 256) m = fmaxf(m, row[k]);
#pragma unroll
    for (int off = 32; off > 0; off >>= 1) m = fmaxf(m, __shfl_down(m, off));
    if (lane == 0) s_red[wave] = m;
    __syncthreads();
    if (tid == 0) s_bc = fmaxf(fmaxf(s_red[0], s_red[1]), fmaxf(s_red[2], s_red[3]));
    __syncthreads();
    m = s_bc;

    float sum = 0.f;
    for (int k = tid; k < V_SZ; k += 256) sum += expf(row[k] - m);
#pragma unroll
    for (int off = 32; off > 0; off >>= 1) sum += __shfl_down(sum, off);
    __syncthreads();
    if (lane == 0) s_red[wave] = sum;
    __syncthreads();
    if (tid == 0) s_bc = logf(s_red[0] + s_red[1] + s_red[2] + s_red[3]) + m;
    __syncthreads();
    const float ls = s_bc;

    for (int k = tid; k < V_SZ; k += 256) row[k] = row[k] - ls;
}

extern "C" void kernel_launch(void* const* d_in, const int* in_sizes, int n_in,
                              void* d_out, int out_size, void* d_ws, size_t ws_size,
                              hipStream_t stream) {
    const float* enc    = (const float*)d_in[0];
    const float* enc_h  = (const float*)d_in[1];
    const int*   tgt    = (const int*)d_in[2];
    const float* emb    = (const float*)d_in[3];
    const float* w1     = (const float*)d_in[4];
    const float* b1     = (const float*)d_in[5];
    const float* w2     = (const float*)d_in[6];
    const float* w_ih   = (const float*)d_in[7];
    const float* w_hh   = (const float*)d_in[8];
    const float* b_ih   = (const float*)d_in[9];
    const float* b_hh   = (const float*)d_in[10];
    const float* out0_w = (const float*)d_in[11];
    const float* out0_b = (const float*)d_in[12];
    const float* out1_w = (const float*)d_in[13];
    const float* out1_b = (const float*)d_in[14];
    float* out = (float*)d_out;

    char* wp = (char*)d_ws;
    auto carve = [&](size_t bytes) { char* p = wp; wp += (bytes + 255) & ~(size_t)255; return p; };
    __hip_bfloat16* enc_bf  = (__hip_bfloat16*)carve((size_t)B_SZ * S_SZ * H_SZ * 2);
    __hip_bfloat16* encp_bf = (__hip_bfloat16*)carve((size_t)B_SZ * S_SZ * H_SZ * 2);
    __hip_bfloat16* w1a_bf  = (__hip_bfloat16*)carve((size_t)H_SZ * H_SZ * 2);        // w1[:, :H]
    __hip_bfloat16* wcat_bf = (__hip_bfloat16*)carve((size_t)NG * H_SZ * 2);          // [w1[:,H:] ; w_hh]
    __hip_bfloat16* wih_bf  = (__hip_bfloat16*)carve((size_t)3 * H_SZ * XW * 2);
    __hip_bfloat16* o0_bf   = (__hip_bfloat16*)carve((size_t)V_SZ * H_SZ * 2);
    __hip_bfloat16* o1_bf   = (__hip_bfloat16*)carve((size_t)V_SZ * H_SZ * 2);
    float*          bias_cat= (float*)carve((size_t)NG * 4);
    float*          h       = (float*)carve((size_t)B_SZ * H_SZ * 4);
    __hip_bfloat16* h_bf    = (__hip_bfloat16*)carve((size_t)B_SZ * H_SZ * 2);
    __hip_bfloat16* hg_bf   = (__hip_bfloat16*)carve((size_t)B_SZ * NG * 2);          // [hproj|gh]
    __hip_bfloat16* x_bf[3];
    for (int t = 0; t < 3; ++t) x_bf[t] = (__hip_bfloat16*)carve((size_t)B_SZ * XW * 2);
    __hip_bfloat16* gi_bf   = (__hip_bfloat16*)carve((size_t)B_SZ * 3 * H_SZ * 2);

    // --- one-time prep ---
    cast_f32_to_bf16<<<2048, 256, 0, stream>>>(enc, H_SZ, H_SZ, enc_bf, B_SZ * S_SZ);
    {
        CastSeg s0{w1,            2 * H_SZ, H_SZ / 4, w1a_bf,                        (long long)H_SZ * H_SZ / 4};
        CastSeg s1{w1 + H_SZ,     2 * H_SZ, H_SZ / 4, wcat_bf,                       (long long)H_SZ * H_SZ / 4};
        CastSeg s2{w_hh,          H_SZ,     H_SZ / 4, wcat_bf + (size_t)H_SZ * H_SZ, (long long)3 * H_SZ * H_SZ / 4};
        CastSeg s3{w_ih,          XW,       XW / 4,   wih_bf,                        (long long)3 * H_SZ * XW / 4};
        CastSeg s4{out0_w,        H_SZ,     H_SZ / 4, o0_bf,                         (long long)V_SZ * H_SZ / 4};
        CastSeg s5{out1_w,        H_SZ,     H_SZ / 4, o1_bf,                         (long long)V_SZ * H_SZ / 4};
        cast_all_kernel<<<2048, 256, 0, stream>>>(s0, s1, s2, s3, s4, s5);
    }
    build_bias_cat<<<NG / 256, 256, 0, stream>>>(b1, b_hh, bias_cat);
    emb_prefill_kernel<<<3 * B_SZ, 128, 0, stream>>>(emb, tgt, x_bf[0], x_bf[1], x_bf[2]);
    h_init_kernel<<<(B_SZ * H_SZ / 4) / 256, 256, 0, stream>>>(enc_h, h, h_bf);

    // enc_proj = enc @ w1[:, :H].T -- 128x256 counted-vmcnt pipeline, 2 blocks/CU, XCD-swizzled
    gemm_bt_pipe128<<<(B_SZ * S_SZ / 128) * (H_SZ / 256), 256, 3 * 24576, stream>>>(
        enc_bf, H_SZ, w1a_bf, H_SZ, encp_bf, H_SZ, H_SZ / 256, H_SZ);

    // hg(0) = h0 @ [w1_h | w_hh].T + [b1 | b_hh]
    gemm_bt_mfma<1, 0><<<(B_SZ / 128) * (NG / 128), 256, 0, stream>>>(
        h_bf, H_SZ, wcat_bf, H_SZ, bias_cat, hg_bf, NG, NG / 128, NG, H_SZ);

    for (int t = 0; t < 3; ++t) {
        attn_ctx_kernel<<<B_SZ, 256, 0, stream>>>(enc_bf, encp_bf, hg_bf, w2, x_bf[t]);

        // gi = x @ w_ih.T + b_ih  (bf16 out)
        gemm_bt_mfma<1, 0><<<(B_SZ / 128) * (3 * H_SZ / 128), 256, 0, stream>>>(
            x_bf[t], XW, wih_bf, XW, b_ih, gi_bf, 3 * H_SZ, 3 * H_SZ / 128, 3 * H_SZ, XW);

        gru_gate_kernel<<<(B_SZ * H_SZ) / 256, 256, 0, stream>>>(gi_bf, hg_bf, h, h_bf);

        // [hg(t+1) | logits(t)] = h @ [wcat | ow].T   (dual output; hg skipped at t==2)
        float* logits = out + (size_t)t * B_SZ * V_SZ;
        const __hip_bfloat16* ow = (t == 1) ? o1_bf : o0_bf;
        const float* ob = (t == 1) ? out1_b : out0_b;
        gemm_dual_mfma<<<(B_SZ / 128) * 64, 256, 0, stream>>>(
            h_bf, wcat_bf, ow, bias_cat, ob, hg_bf, logits, (t < 2) ? 1 : 0);

        logsoftmax_kernel<<<B_SZ, 256, 0, stream>>>(logits);
    }
}

// Round 7
// 538.050 us; speedup vs baseline: 7.3478x; 1.0347x over previous
//
#include <hip/hip_runtime.h>
#include <hip/hip_bf16.h>
#include <math.h>

#define B_SZ 1024
#define S_SZ 40
#define H_SZ 1024
#define DW_SZ 512
#define V_SZ 4000
#define XW (DW_SZ + H_SZ)      // 1536
#define NG (4 * H_SZ)          // 4096: [hproj | gh(3H)]

typedef __bf16 bf16x8 __attribute__((ext_vector_type(8)));
typedef float f32x4 __attribute__((ext_vector_type(4)));

__device__ __forceinline__ float fast_tanh(float x) {
    return 1.0f - 2.0f / (1.0f + __expf(2.0f * x));
}
__device__ __forceinline__ float fast_sigmoid(float x) {
    return 1.0f / (1.0f + __expf(-x));
}
__device__ __forceinline__ float bfraw2f(unsigned short u) {
    return __uint_as_float(((unsigned)u) << 16);
}

#define GLL16(gp, lp)                                                                \
    __builtin_amdgcn_global_load_lds((const __attribute__((address_space(1))) void*)(gp), \
                                     (__attribute__((address_space(3))) void*)(lp), 16, 0, 0)

// ========== 128x256 tile, BK=32, 3-slot counted-vmcnt pipelined GEMM, 2 blocks/CU ==========
__global__ __launch_bounds__(256, 2) void gemm_bt_pipe128(
    const __hip_bfloat16* __restrict__ A, int lda,
    const __hip_bfloat16* __restrict__ W, int ldw,
    __hip_bfloat16* __restrict__ C, int ldc,
    int nbx, int K) {
    extern __shared__ char smem[];   // 3 * 24576 bytes
    const int tid = threadIdx.x;
    const int lane = tid & 63;
    const int wave = tid >> 6;
    const int wm = wave >> 1, wn = wave & 1;
    const int fr = lane & 15, fq = lane >> 4;

    int bid = blockIdx.x;
    { const int cpx = gridDim.x >> 3; bid = (bid & 7) * cpx + (bid >> 3); }  // XCD swizzle
    const int by = bid / nbx;
    const int bm = by * 128;
    const int bn = (bid - by * nbx) * 256;

    const int r0 = tid >> 2;
    const int s0 = (tid & 3) ^ ((tid >> 3) & 3);
    const __hip_bfloat16* gA0 = A + (size_t)(bm + r0) * lda + s0 * 8;
    const __hip_bfloat16* gA1 = A + (size_t)(bm + r0 + 64) * lda + s0 * 8;
    const __hip_bfloat16* gW0 = W + (size_t)(bn + r0) * ldw + s0 * 8;
    const __hip_bfloat16* gW1 = W + (size_t)(bn + r0 + 64) * ldw + s0 * 8;
    const __hip_bfloat16* gW2 = W + (size_t)(bn + r0 + 128) * ldw + s0 * 8;
    const __hip_bfloat16* gW3 = W + (size_t)(bn + r0 + 192) * ldw + s0 * 8;
    const int dst0 = tid * 16;

    int aoff[4], boff[8];
#pragma unroll
    for (int mi = 0; mi < 4; ++mi) {
        const int row = wm * 64 + mi * 16 + fr;
        aoff[mi] = row * 64 + ((fq ^ ((row >> 1) & 3)) << 4);
    }
#pragma unroll
    for (int ni = 0; ni < 8; ++ni) {
        const int col = wn * 128 + ni * 16 + fr;
        boff[ni] = 8192 + col * 64 + ((fq ^ ((col >> 1) & 3)) << 4);
    }

    const int NT = K >> 5;
    f32x4 acc[4][8] = {};

#define STAGE_T(t)                                                    \
    do {                                                              \
        char* sb = smem + ((t) % 3) * 24576;                          \
        const int kk = (t) << 5;                                      \
        GLL16(gA0 + kk, sb + dst0);                                   \
        GLL16(gA1 + kk, sb + dst0 + 4096);                            \
        GLL16(gW0 + kk, sb + 8192 + dst0);                            \
        GLL16(gW1 + kk, sb + 8192 + dst0 + 4096);                     \
        GLL16(gW2 + kk, sb + 8192 + dst0 + 8192);                     \
        GLL16(gW3 + kk, sb + 8192 + dst0 + 12288);                    \
    } while (0)

    STAGE_T(0);
    STAGE_T(1);
    __builtin_amdgcn_sched_barrier(0);
    asm volatile("s_waitcnt vmcnt(6)" ::: "memory");
    __builtin_amdgcn_s_barrier();
    __builtin_amdgcn_sched_barrier(0);

    for (int t = 0; t < NT; ++t) {
        const char* sb = smem + (t % 3) * 24576;
        bf16x8 af[4], bg[8];
#pragma unroll
        for (int ni = 0; ni < 8; ++ni) bg[ni] = *reinterpret_cast<const bf16x8*>(sb + boff[ni]);
#pragma unroll
        for (int mi = 0; mi < 4; ++mi) af[mi] = *reinterpret_cast<const bf16x8*>(sb + aoff[mi]);

        if (t + 2 < NT) STAGE_T(t + 2);

        __builtin_amdgcn_s_setprio(1);
#pragma unroll
        for (int mi = 0; mi < 4; ++mi)
#pragma unroll
            for (int ni = 0; ni < 8; ++ni)
                acc[mi][ni] = __builtin_amdgcn_mfma_f32_16x16x32_bf16(af[mi], bg[ni], acc[mi][ni], 0, 0, 0);
        __builtin_amdgcn_s_setprio(0);

        if (t != NT - 1) {
            __builtin_amdgcn_sched_barrier(0);
            if (t + 2 < NT) asm volatile("s_waitcnt vmcnt(6)" ::: "memory");
            else            asm volatile("s_waitcnt vmcnt(0)" ::: "memory");
            __builtin_amdgcn_s_barrier();
            __builtin_amdgcn_sched_barrier(0);
        }
    }
#undef STAGE_T

#pragma unroll
    for (int mi = 0; mi < 4; ++mi) {
        const int row0 = bm + wm * 64 + mi * 16 + fq * 4;
#pragma unroll
        for (int ni = 0; ni < 8; ++ni) {
            const int col = bn + wn * 128 + ni * 16 + fr;
#pragma unroll
            for (int r = 0; r < 4; ++r)
                C[(size_t)(row0 + r) * ldc + col] = __float2bfloat16(acc[mi][ni][r]);
        }
    }
}

// ---------------- bf16 MFMA GEMM (128x128, 2-barrier): C = A@W.T + bias ----------------
template <int OB, int SWZ>
__global__ __launch_bounds__(256) void gemm_bt_mfma(
    const __hip_bfloat16* __restrict__ A, int lda,
    const __hip_bfloat16* __restrict__ W, int ldw,
    const float* __restrict__ bias,
    void* __restrict__ Cv, int ldc,
    int nbx, int N, int K) {
    __shared__ __align__(16) __hip_bfloat16 As[128 * 32];
    __shared__ __align__(16) __hip_bfloat16 Ws[128 * 32];
    const int tid = threadIdx.x;
    const int lane = tid & 63;
    const int wave = tid >> 6;

    int bid = blockIdx.x;
    if (SWZ) {
        const int cpx = gridDim.x >> 3;
        bid = (bid & 7) * cpx + (bid >> 3);
    }
    const int by = bid / nbx;
    const int bx = bid - by * nbx;
    const int bm = by * 128;
    const int bn = bx * 128;

    const int r0 = tid >> 2;
    const int kk = (tid & 3) * 8;
    const __hip_bfloat16* gA0 = A + (size_t)(bm + r0) * lda + kk;
    const __hip_bfloat16* gA1 = gA0 + (size_t)64 * lda;
    int wrow0 = bn + r0;      if (wrow0 > N - 1) wrow0 = N - 1;
    int wrow1 = bn + r0 + 64; if (wrow1 > N - 1) wrow1 = N - 1;
    const __hip_bfloat16* gW0 = W + (size_t)wrow0 * ldw + kk;
    const __hip_bfloat16* gW1 = W + (size_t)wrow1 * ldw + kk;
    char* As_c = (char*)As + tid * 16;
    char* Ws_c = (char*)Ws + tid * 16;

    const int wr = wave >> 1, wc = wave & 1;
    const int fr = lane & 15, fq = lane >> 4;
    const __hip_bfloat16* Ard = &As[(wr * 64 + fr) * 32 + fq * 8];
    const __hip_bfloat16* Wrd = &Ws[(wc * 64 + fr) * 32 + fq * 8];

    f32x4 acc[4][4] = {};

    for (int k0 = 0; k0 < K; k0 += 32) {
        __syncthreads();
        GLL16(gA0 + k0, As_c);
        GLL16(gA1 + k0, As_c + 4096);
        GLL16(gW0 + k0, Ws_c);
        GLL16(gW1 + k0, Ws_c + 4096);
        __syncthreads();

        bf16x8 af[4], bg[4];
#pragma unroll
        for (int i = 0; i < 4; ++i) {
            af[i] = *reinterpret_cast<const bf16x8*>(Ard + i * 16 * 32);
            bg[i] = *reinterpret_cast<const bf16x8*>(Wrd + i * 16 * 32);
        }
#pragma unroll
        for (int mi = 0; mi < 4; ++mi)
#pragma unroll
            for (int ni = 0; ni < 4; ++ni)
                acc[mi][ni] = __builtin_amdgcn_mfma_f32_16x16x32_bf16(af[mi], bg[ni], acc[mi][ni], 0, 0, 0);
    }

#pragma unroll
    for (int ni = 0; ni < 4; ++ni) {
        const int col = bn + wc * 64 + ni * 16 + fr;
        if (col >= N) continue;
        const float bb = bias ? bias[col] : 0.0f;
#pragma unroll
        for (int mi = 0; mi < 4; ++mi) {
            const int row0 = bm + wr * 64 + mi * 16 + fq * 4;
#pragma unroll
            for (int r = 0; r < 4; ++r) {
                const float v = acc[mi][ni][r] + bb;
                if (OB)
                    reinterpret_cast<__hip_bfloat16*>(Cv)[(size_t)(row0 + r) * ldc + col] = __float2bfloat16(v);
                else
                    reinterpret_cast<float*>(Cv)[(size_t)(row0 + r) * ldc + col] = v;
            }
        }
    }
}

// ---------------- dual GEMM: cols [0,4096) -> hg (bf16); cols [4096,..) -> logits (bf16) ----------------
__global__ __launch_bounds__(256) void gemm_dual_mfma(
    const __hip_bfloat16* __restrict__ A,
    const __hip_bfloat16* __restrict__ Wg,
    const __hip_bfloat16* __restrict__ Wo,
    const float* __restrict__ bias_cat,
    const float* __restrict__ ob,
    __hip_bfloat16* __restrict__ hg,
    __hip_bfloat16* __restrict__ lg,   // bf16 logits [B][V]
    int full) {
    const int nbx = 64;
    const int bid = blockIdx.x;
    const int by = bid / nbx;
    const int bx = bid - by * nbx;
    const int bm = by * 128;
    const int bn = bx * 128;
    const int is_hg = (bn < NG);
    if (!full && is_hg) return;

    __shared__ __align__(16) __hip_bfloat16 As[128 * 32];
    __shared__ __align__(16) __hip_bfloat16 Ws[128 * 32];
    const int tid = threadIdx.x;
    const int lane = tid & 63;
    const int wave = tid >> 6;

    const __hip_bfloat16* Wb = is_hg ? Wg : Wo;
    const int coff = is_hg ? bn : bn - NG;
    const int nn = is_hg ? NG : V_SZ;

    const int r0 = tid >> 2;
    const int kk = (tid & 3) * 8;
    const __hip_bfloat16* gA0 = A + (size_t)(bm + r0) * H_SZ + kk;
    const __hip_bfloat16* gA1 = gA0 + (size_t)64 * H_SZ;
    int wrow0 = coff + r0;      if (wrow0 > nn - 1) wrow0 = nn - 1;
    int wrow1 = coff + r0 + 64; if (wrow1 > nn - 1) wrow1 = nn - 1;
    const __hip_bfloat16* gW0 = Wb + (size_t)wrow0 * H_SZ + kk;
    const __hip_bfloat16* gW1 = Wb + (size_t)wrow1 * H_SZ + kk;
    char* As_c = (char*)As + tid * 16;
    char* Ws_c = (char*)Ws + tid * 16;

    const int wr = wave >> 1, wc = wave & 1;
    const int fr = lane & 15, fq = lane >> 4;
    const __hip_bfloat16* Ard = &As[(wr * 64 + fr) * 32 + fq * 8];
    const __hip_bfloat16* Wrd = &Ws[(wc * 64 + fr) * 32 + fq * 8];

    f32x4 acc[4][4] = {};

    for (int k0 = 0; k0 < H_SZ; k0 += 32) {
        __syncthreads();
        GLL16(gA0 + k0, As_c);
        GLL16(gA1 + k0, As_c + 4096);
        GLL16(gW0 + k0, Ws_c);
        GLL16(gW1 + k0, Ws_c + 4096);
        __syncthreads();

        bf16x8 af[4], bg[4];
#pragma unroll
        for (int i = 0; i < 4; ++i) {
            af[i] = *reinterpret_cast<const bf16x8*>(Ard + i * 16 * 32);
            bg[i] = *reinterpret_cast<const bf16x8*>(Wrd + i * 16 * 32);
        }
#pragma unroll
        for (int mi = 0; mi < 4; ++mi)
#pragma unroll
            for (int ni = 0; ni < 4; ++ni)
                acc[mi][ni] = __builtin_amdgcn_mfma_f32_16x16x32_bf16(af[mi], bg[ni], acc[mi][ni], 0, 0, 0);
    }

#pragma unroll
    for (int ni = 0; ni < 4; ++ni) {
        const int cl = coff + wc * 64 + ni * 16 + fr;
        if (cl >= nn) continue;
        const float bb = is_hg ? bias_cat[cl] : ob[cl];
#pragma unroll
        for (int mi = 0; mi < 4; ++mi) {
            const int row0 = bm + wr * 64 + mi * 16 + fq * 4;
#pragma unroll
            for (int r = 0; r < 4; ++r) {
                const float v = acc[mi][ni][r] + bb;
                if (is_hg)
                    hg[(size_t)(row0 + r) * NG + cl] = __float2bfloat16(v);
                else
                    lg[(size_t)(row0 + r) * V_SZ + cl] = __float2bfloat16(v);
            }
        }
    }
}

// ---------------- unified cast: 7 segments (weights + enc) ----------------
struct CastSeg { const float* src; long long sstride; int c4n; __hip_bfloat16* dst; long long n4; };
__global__ __launch_bounds__(256) void cast_all_kernel(CastSeg s0, CastSeg s1, CastSeg s2,
                                                       CastSeg s3, CastSeg s4, CastSeg s5, CastSeg s6) {
    const long long e0 = s0.n4, e1 = e0 + s1.n4, e2 = e1 + s2.n4,
                    e3 = e2 + s3.n4, e4 = e3 + s4.n4, e5 = e4 + s5.n4, e6 = e5 + s6.n4;
    for (long long i = (long long)blockIdx.x * 256 + threadIdx.x; i < e6;
         i += (long long)gridDim.x * 256) {
        CastSeg sg; long long li = i;
        if (i < e0) { sg = s0; }
        else if (i < e1) { sg = s1; li -= e0; }
        else if (i < e2) { sg = s2; li -= e1; }
        else if (i < e3) { sg = s3; li -= e2; }
        else if (i < e4) { sg = s4; li -= e3; }
        else if (i < e5) { sg = s5; li -= e4; }
        else { sg = s6; li -= e5; }
        const long long r = li / sg.c4n;
        const int c = (int)(li - r * sg.c4n) << 2;
        const float4 v = *reinterpret_cast<const float4*>(sg.src + r * sg.sstride + c);
        union { ushort4 u; __hip_bfloat16 h[4]; } o;
        o.h[0] = __float2bfloat16(v.x); o.h[1] = __float2bfloat16(v.y);
        o.h[2] = __float2bfloat16(v.z); o.h[3] = __float2bfloat16(v.w);
        *reinterpret_cast<ushort4*>(sg.dst + r * (long long)(sg.c4n << 2) + c) = o.u;
    }
}

// ---------------- small prep: emb prefill (blk<3072), h init (3072..4095), bias_cat (4096) ----------------
__global__ __launch_bounds__(256) void small_prep_kernel(
    const float* __restrict__ emb, const int* __restrict__ targets,
    __hip_bfloat16* __restrict__ x0, __hip_bfloat16* __restrict__ x1, __hip_bfloat16* __restrict__ x2,
    const float* __restrict__ enc_h, float* __restrict__ h, __hip_bfloat16* __restrict__ h_bf,
    const float* __restrict__ b1, const float* __restrict__ b_hh, float* __restrict__ bias_cat) {
    const int blk = blockIdx.x;
    const int tid = threadIdx.x;
    if (blk < 3072) {
        if (tid >= 128) return;
        const int t = blk >> 10;
        const int b = blk & 1023;
        int it; __hip_bfloat16* x;
        if (t == 0) { it = 0; x = x0; }
        else if (t == 1) { it = targets[b] + 1; x = x1; }
        else { it = targets[B_SZ + b] + 36; x = x2; }
        float4 v = reinterpret_cast<const float4*>(emb + (size_t)it * DW_SZ)[tid];
        union { ushort4 u; __hip_bfloat16 hh[4]; } o;
        o.hh[0] = __float2bfloat16(v.x); o.hh[1] = __float2bfloat16(v.y);
        o.hh[2] = __float2bfloat16(v.z); o.hh[3] = __float2bfloat16(v.w);
        reinterpret_cast<ushort4*>(x + (size_t)b * XW)[tid] = o.u;
    } else if (blk < 4096) {
        const int i = (blk - 3072) * 256 + tid;   // over B*H/4
        const float4 v = reinterpret_cast<const float4*>(enc_h)[i];
        reinterpret_cast<float4*>(h)[i] = v;
        union { ushort4 u; __hip_bfloat16 hh[4]; } o;
        o.hh[0] = __float2bfloat16(v.x); o.hh[1] = __float2bfloat16(v.y);
        o.hh[2] = __float2bfloat16(v.z); o.hh[3] = __float2bfloat16(v.w);
        reinterpret_cast<ushort4*>(h_bf)[i] = o.u;
    } else {
        for (int j = tid; j < NG; j += 256)
            bias_cat[j] = (j < H_SZ) ? b1[j] : b_hh[j - H_SZ];
    }
}

// ---------------- fused: blocks [0,nattn) = attention for step t+1; rest = log-softmax of step t ----------------
__global__ __launch_bounds__(256) void attn_ls_kernel(
    const __hip_bfloat16* __restrict__ enc,
    const __hip_bfloat16* __restrict__ enc_proj,
    const __hip_bfloat16* __restrict__ hg,
    const float* __restrict__ w2,
    __hip_bfloat16* __restrict__ x,            // attn output target
    const __hip_bfloat16* __restrict__ lg,     // bf16 logits in
    float* __restrict__ outp,                  // f32 log-probs out
    int nattn) {
    const int blk = blockIdx.x;
    const int tid = threadIdx.x;
    const int lane = tid & 63, wave = tid >> 6;
    __shared__ float s_e[S_SZ];
    __shared__ float s_red[4];
    __shared__ float s_bc;

    if (blk < nattn) {
        // ---- attention ----
        const int b = blk;
        float hp[16], wv[16];
        const unsigned short* hgrow = reinterpret_cast<const unsigned short*>(hg) + (size_t)b * NG;
#pragma unroll
        for (int p = 0; p < 4; ++p) {
            const int base = p * 256 + lane * 4;
            ushort4 hu = *reinterpret_cast<const ushort4*>(hgrow + base);
            float4 wq = *reinterpret_cast<const float4*>(w2 + base);
            hp[p * 4 + 0] = bfraw2f(hu.x); hp[p * 4 + 1] = bfraw2f(hu.y);
            hp[p * 4 + 2] = bfraw2f(hu.z); hp[p * 4 + 3] = bfraw2f(hu.w);
            wv[p * 4 + 0] = wq.x; wv[p * 4 + 1] = wq.y;
            wv[p * 4 + 2] = wq.z; wv[p * 4 + 3] = wq.w;
        }

        const unsigned short* ep0 = reinterpret_cast<const unsigned short*>(enc_proj) + (size_t)b * S_SZ * H_SZ;
#pragma unroll 2
        for (int i = 0; i < 10; ++i) {
            const int s = wave + 4 * i;
            const unsigned short* row = ep0 + (size_t)s * H_SZ;
            float acc = 0.f;
#pragma unroll
            for (int p = 0; p < 4; ++p) {
                ushort4 eu = *reinterpret_cast<const ushort4*>(row + p * 256 + lane * 4);
                acc += fast_tanh(bfraw2f(eu.x) + hp[p * 4 + 0]) * wv[p * 4 + 0]
                     + fast_tanh(bfraw2f(eu.y) + hp[p * 4 + 1]) * wv[p * 4 + 1]
                     + fast_tanh(bfraw2f(eu.z) + hp[p * 4 + 2]) * wv[p * 4 + 2]
                     + fast_tanh(bfraw2f(eu.w) + hp[p * 4 + 3]) * wv[p * 4 + 3];
            }
#pragma unroll
            for (int off = 32; off > 0; off >>= 1) acc += __shfl_down(acc, off);
            if (lane == 0) s_e[s] = acc;
        }
        __syncthreads();

        float m = -1e30f;
        for (int s = 0; s < S_SZ; ++s) m = fmaxf(m, s_e[s]);
        float sum = 0.f;
        for (int s = 0; s < S_SZ; ++s) sum += __expf(s_e[s] - m);
        const float inv = 1.0f / sum;

        const ushort4* enc_b = reinterpret_cast<const ushort4*>(enc + (size_t)b * S_SZ * H_SZ);
        float4 acc = make_float4(0.f, 0.f, 0.f, 0.f);
        for (int s = 0; s < S_SZ; ++s) {
            const float a = __expf(s_e[s] - m) * inv;
            ushort4 ev = enc_b[s * 256 + tid];
            acc.x += a * bfraw2f(ev.x); acc.y += a * bfraw2f(ev.y);
            acc.z += a * bfraw2f(ev.z); acc.w += a * bfraw2f(ev.w);
        }
        union { ushort4 u; __hip_bfloat16 hh[4]; } o;
        o.hh[0] = __float2bfloat16(acc.x); o.hh[1] = __float2bfloat16(acc.y);
        o.hh[2] = __float2bfloat16(acc.z); o.hh[3] = __float2bfloat16(acc.w);
        reinterpret_cast<ushort4*>(x + (size_t)b * XW + DW_SZ)[tid] = o.u;
    } else {
        // ---- log-softmax (bf16 logits -> f32 out) ----
        const int b = blk - nattn;
        const ushort4* row4 = reinterpret_cast<const ushort4*>(
            reinterpret_cast<const unsigned short*>(lg) + (size_t)b * V_SZ);
        float* orow = outp + (size_t)b * V_SZ;

        float m = -1e30f;
        for (int k = tid; k < V_SZ / 4; k += 256) {
            ushort4 u = row4[k];
            m = fmaxf(m, fmaxf(fmaxf(bfraw2f(u.x), bfraw2f(u.y)), fmaxf(bfraw2f(u.z), bfraw2f(u.w))));
        }
#pragma unroll
        for (int off = 32; off > 0; off >>= 1) m = fmaxf(m, __shfl_down(m, off));
        if (lane == 0) s_red[wave] = m;
        __syncthreads();
        if (tid == 0) s_bc = fmaxf(fmaxf(s_red[0], s_red[1]), fmaxf(s_red[2], s_red[3]));
        __syncthreads();
        m = s_bc;

        float sum = 0.f;
        for (int k = tid; k < V_SZ / 4; k += 256) {
            ushort4 u = row4[k];
            sum += expf(bfraw2f(u.x) - m) + expf(bfraw2f(u.y) - m)
                 + expf(bfraw2f(u.z) - m) + expf(bfraw2f(u.w) - m);
        }
#pragma unroll
        for (int off = 32; off > 0; off >>= 1) sum += __shfl_down(sum, off);
        __syncthreads();
        if (lane == 0) s_red[wave] = sum;
        __syncthreads();
        if (tid == 0) s_bc = logf(s_red[0] + s_red[1] + s_red[2] + s_red[3]) + m;
        __syncthreads();
        const float ls = s_bc;

        for (int k = tid; k < V_SZ / 4; k += 256) {
            ushort4 u = row4[k];
            float4 o = make_float4(bfraw2f(u.x) - ls, bfraw2f(u.y) - ls,
                                   bfraw2f(u.z) - ls, bfraw2f(u.w) - ls);
            reinterpret_cast<float4*>(orow)[k] = o;
        }
    }
}

// ---------------- GRU gate combine ----------------
__global__ __launch_bounds__(256) void gru_gate_kernel(
    const __hip_bfloat16* __restrict__ gi,
    const __hip_bfloat16* __restrict__ hg,
    float* __restrict__ h,
    __hip_bfloat16* __restrict__ h_bf) {
    const int idx = blockIdx.x * 256 + threadIdx.x;
    const int b = idx >> 10;
    const int j = idx & 1023;
    const unsigned short* gib = reinterpret_cast<const unsigned short*>(gi) + (size_t)b * 3 * H_SZ;
    const unsigned short* ghb = reinterpret_cast<const unsigned short*>(hg) + (size_t)b * NG + H_SZ;
    const float i_r = bfraw2f(gib[j]), i_z = bfraw2f(gib[H_SZ + j]), i_n = bfraw2f(gib[2 * H_SZ + j]);
    const float h_r = bfraw2f(ghb[j]), h_z = bfraw2f(ghb[H_SZ + j]), h_n = bfraw2f(ghb[2 * H_SZ + j]);
    const float r = fast_sigmoid(i_r + h_r);
    const float z = fast_sigmoid(i_z + h_z);
    const float n = fast_tanh(i_n + r * h_n);
    const float hv = (1.0f - z) * n + z * h[idx];
    h[idx] = hv;
    h_bf[idx] = __float2bfloat16(hv);
}

extern "C" void kernel_launch(void* const* d_in, const int* in_sizes, int n_in,
                              void* d_out, int out_size, void* d_ws, size_t ws_size,
                              hipStream_t stream) {
    const float* enc    = (const float*)d_in[0];
    const float* enc_h  = (const float*)d_in[1];
    const int*   tgt    = (const int*)d_in[2];
    const float* emb    = (const float*)d_in[3];
    const float* w1     = (const float*)d_in[4];
    const float* b1     = (const float*)d_in[5];
    const float* w2     = (const float*)d_in[6];
    const float* w_ih   = (const float*)d_in[7];
    const float* w_hh   = (const float*)d_in[8];
    const float* b_ih   = (const float*)d_in[9];
    const float* b_hh   = (const float*)d_in[10];
    const float* out0_w = (const float*)d_in[11];
    const float* out0_b = (const float*)d_in[12];
    const float* out1_w = (const float*)d_in[13];
    const float* out1_b = (const float*)d_in[14];
    float* out = (float*)d_out;

    char* wp = (char*)d_ws;
    auto carve = [&](size_t bytes) { char* p = wp; wp += (bytes + 255) & ~(size_t)255; return p; };
    __hip_bfloat16* enc_bf  = (__hip_bfloat16*)carve((size_t)B_SZ * S_SZ * H_SZ * 2);
    __hip_bfloat16* encp_bf = (__hip_bfloat16*)carve((size_t)B_SZ * S_SZ * H_SZ * 2);
    __hip_bfloat16* w1a_bf  = (__hip_bfloat16*)carve((size_t)H_SZ * H_SZ * 2);
    __hip_bfloat16* wcat_bf = (__hip_bfloat16*)carve((size_t)NG * H_SZ * 2);
    __hip_bfloat16* wih_bf  = (__hip_bfloat16*)carve((size_t)3 * H_SZ * XW * 2);
    __hip_bfloat16* o0_bf   = (__hip_bfloat16*)carve((size_t)V_SZ * H_SZ * 2);
    __hip_bfloat16* o1_bf   = (__hip_bfloat16*)carve((size_t)V_SZ * H_SZ * 2);
    float*          bias_cat= (float*)carve((size_t)NG * 4);
    float*          h       = (float*)carve((size_t)B_SZ * H_SZ * 4);
    __hip_bfloat16* h_bf    = (__hip_bfloat16*)carve((size_t)B_SZ * H_SZ * 2);
    __hip_bfloat16* hg_bf   = (__hip_bfloat16*)carve((size_t)B_SZ * NG * 2);
    __hip_bfloat16* x_bf[3];
    for (int t = 0; t < 3; ++t) x_bf[t] = (__hip_bfloat16*)carve((size_t)B_SZ * XW * 2);
    __hip_bfloat16* gi_bf   = (__hip_bfloat16*)carve((size_t)B_SZ * 3 * H_SZ * 2);
    __hip_bfloat16* lg_bf   = (__hip_bfloat16*)carve((size_t)B_SZ * V_SZ * 2);

    // --- prep: 2 launches ---
    {
        CastSeg s0{w1,        2 * H_SZ, H_SZ / 4, w1a_bf,                        (long long)H_SZ * H_SZ / 4};
        CastSeg s1{w1 + H_SZ, 2 * H_SZ, H_SZ / 4, wcat_bf,                       (long long)H_SZ * H_SZ / 4};
        CastSeg s2{w_hh,      H_SZ,     H_SZ / 4, wcat_bf + (size_t)H_SZ * H_SZ, (long long)3 * H_SZ * H_SZ / 4};
        CastSeg s3{w_ih,      XW,       XW / 4,   wih_bf,                        (long long)3 * H_SZ * XW / 4};
        CastSeg s4{out0_w,    H_SZ,     H_SZ / 4, o0_bf,                         (long long)V_SZ * H_SZ / 4};
        CastSeg s5{out1_w,    H_SZ,     H_SZ / 4, o1_bf,                         (long long)V_SZ * H_SZ / 4};
        CastSeg s6{enc,       H_SZ,     H_SZ / 4, enc_bf,                        (long long)B_SZ * S_SZ * H_SZ / 4};
        cast_all_kernel<<<4096, 256, 0, stream>>>(s0, s1, s2, s3, s4, s5, s6);
    }
    small_prep_kernel<<<4097, 256, 0, stream>>>(emb, tgt, x_bf[0], x_bf[1], x_bf[2],
                                                enc_h, h, h_bf, b1, b_hh, bias_cat);

    // enc_proj = enc @ w1[:, :H].T -- 128x256 counted-vmcnt pipeline, XCD-swizzled
    gemm_bt_pipe128<<<(B_SZ * S_SZ / 128) * (H_SZ / 256), 256, 3 * 24576, stream>>>(
        enc_bf, H_SZ, w1a_bf, H_SZ, encp_bf, H_SZ, H_SZ / 256, H_SZ);

    // hg(0) = h0 @ [w1_h | w_hh].T + [b1 | b_hh]
    gemm_bt_mfma<1, 0><<<(B_SZ / 128) * (NG / 128), 256, 0, stream>>>(
        h_bf, H_SZ, wcat_bf, H_SZ, bias_cat, hg_bf, NG, NG / 128, NG, H_SZ);

    // attn(0) standalone (nattn = grid, no ls part)
    attn_ls_kernel<<<B_SZ, 256, 0, stream>>>(enc_bf, encp_bf, hg_bf, w2, x_bf[0],
                                             lg_bf, out, B_SZ);

    for (int t = 0; t < 3; ++t) {
        // gi = x @ w_ih.T + b_ih  (bf16 out)
        gemm_bt_mfma<1, 0><<<(B_SZ / 128) * (3 * H_SZ / 128), 256, 0, stream>>>(
            x_bf[t], XW, wih_bf, XW, b_ih, gi_bf, 3 * H_SZ, 3 * H_SZ / 128, 3 * H_SZ, XW);

        gru_gate_kernel<<<(B_SZ * H_SZ) / 256, 256, 0, stream>>>(gi_bf, hg_bf, h, h_bf);

        // [hg(t+1) | logits_bf16(t)] = h @ [wcat | ow].T   (hg skipped at t==2)
        const __hip_bfloat16* ow = (t == 1) ? o1_bf : o0_bf;
        const float* ob = (t == 1) ? out1_b : out0_b;
        gemm_dual_mfma<<<(B_SZ / 128) * 64, 256, 0, stream>>>(
            h_bf, wcat_bf, ow, bias_cat, ob, hg_bf, lg_bf, (t < 2) ? 1 : 0);

        // fused: log-softmax(t) [+ attention(t+1) when t<2]
        float* outp = out + (size_t)t * B_SZ * V_SZ;
        if (t < 2) {
            attn_ls_kernel<<<2 * B_SZ, 256, 0, stream>>>(enc_bf, encp_bf, hg_bf, w2, x_bf[t + 1],
                                                         lg_bf, outp, B_SZ);
        } else {
            attn_ls_kernel<<<B_SZ, 256, 0, stream>>>(enc_bf, encp_bf, hg_bf, w2, x_bf[0],
                                                     lg_bf, outp, 0);
        }
    }
}